// Round 4
// baseline (3646.309 us; speedup 1.0000x reference)
//
#include <hip/hip_runtime.h>

#define EMB      128
#define N_NODES_ 50000
#define N_EDGES_ 800000
#define N_GRAPH_ 256
#define NLAYER_  5

// packed-weight layout offsets (ushort elements)
#define WP_ATOM  573440
#define WP_NODE0 589824
#define WP_EMB   671744
#define WP_TOTAL 675840

typedef short short8 __attribute__((ext_vector_type(8)));
typedef float floatx4 __attribute__((ext_vector_type(4)));
typedef unsigned uintx2 __attribute__((ext_vector_type(2)));

__device__ __forceinline__ float silu_f(float x) {
    return __fdividef(x, 1.0f + __expf(-x));
}
__device__ __forceinline__ float bf2f(unsigned short h) {
    return __uint_as_float(((unsigned)h) << 16);
}
__device__ __forceinline__ unsigned short f2bf(float f) {
    unsigned u = __float_as_uint(f);
    unsigned r = 0x7FFFu + ((u >> 16) & 1u);
    return (unsigned short)((u + r) >> 16);
}

#if defined(__has_builtin)
#if __has_builtin(__builtin_amdgcn_cvt_pk_bf16_f32)
#define HAVE_PK_BF16 1
#endif
#if __has_builtin(__builtin_amdgcn_permlane16_swap) && __has_builtin(__builtin_amdgcn_permlane32_swap)
#define HAVE_PERMLANE_SWAP 1
#endif
#endif

#ifdef HAVE_PK_BF16
typedef __bf16 bf16x2 __attribute__((ext_vector_type(2)));
__device__ __forceinline__ unsigned f2bf_pk(float a, float b) {
    bf16x2 v = __builtin_amdgcn_cvt_pk_bf16_f32(a, b);
    unsigned u;
    __builtin_memcpy(&u, &v, 4);
    return u;
}
#else
__device__ __forceinline__ unsigned f2bf_pk(float a, float b) {
    return (unsigned)f2bf(a) | ((unsigned)f2bf(b) << 16);
}
#endif

// wave-local LDS ordering (validated round 9: correctness held)
__device__ __forceinline__ void wave_lds_fence() {
    __builtin_amdgcn_fence(__ATOMIC_ACQ_REL, "wavefront");
    __builtin_amdgcn_wave_barrier();
}

// ---------------------------------------------------------------------------
// In-wave 16-lane-row exchanges (gfx950 permlane*_swap; ds-op fallback).
// swap32: vdst rows{2,3} <-> vsrc rows{0,1}.  swap16: vdst odd rows <-> vsrc
// even rows. Used to convert MFMA C-fragment packs into next-stage B-frags.
// ---------------------------------------------------------------------------
__device__ __forceinline__ void swap32(unsigned &a, unsigned &b) {
#ifdef HAVE_PERMLANE_SWAP
    uintx2 r = __builtin_amdgcn_permlane32_swap(a, b, false, false);
    a = r.x; b = r.y;
#else
    const int lane = (int)(threadIdx.x & 63);
    const int idx = (lane ^ 32) << 2;
    const unsigned ta = (unsigned)__builtin_amdgcn_ds_bpermute(idx, (int)a);
    const unsigned tb = (unsigned)__builtin_amdgcn_ds_bpermute(idx, (int)b);
    const bool hi = lane >= 32;
    const unsigned na = hi ? tb : a;
    const unsigned nb = hi ? b : ta;
    a = na; b = nb;
#endif
}
__device__ __forceinline__ void swap16(unsigned &a, unsigned &b) {
#ifdef HAVE_PERMLANE_SWAP
    uintx2 r = __builtin_amdgcn_permlane16_swap(a, b, false, false);
    a = r.x; b = r.y;
#else
    const unsigned ta = (unsigned)__builtin_amdgcn_ds_swizzle((int)a, 0x401F); // lane^16
    const unsigned tb = (unsigned)__builtin_amdgcn_ds_swizzle((int)b, 0x401F);
    const bool odd = ((threadIdx.x >> 4) & 1) != 0;
    const unsigned na = odd ? tb : a;
    const unsigned nb = odd ? b : ta;
    a = na; b = nb;
#endif
}

// C-frag packs of n-tiles (2kb, 2kb+1) -> B-fragment short8 for k-block kb.
__device__ __forceinline__ short8 xchg_frag(uint2 pkE, uint2 pkO) {
    unsigned a0 = pkE.x, b0 = pkO.x;   // element pairs {0,1} of both tiles
    unsigned a1 = pkE.y, b1 = pkO.y;   // element pairs {2,3}
    swap32(a0, b0); swap16(a0, b0);    // -> u[0], u[2]
    swap32(a1, b1); swap16(a1, b1);    // -> u[1], u[3]
    union { short8 s; unsigned u[4]; } r;
    r.u[0] = a0; r.u[1] = a1; r.u[2] = b0; r.u[3] = b1;
    return r.s;
}

__device__ __forceinline__ floatx4 upair_sum(uint2 a, uint2 b) {
    floatx4 r;
    r[0] = bf2f((unsigned short)(a.x & 0xFFFF)) + bf2f((unsigned short)(b.x & 0xFFFF));
    r[1] = bf2f((unsigned short)(a.x >> 16))    + bf2f((unsigned short)(b.x >> 16));
    r[2] = bf2f((unsigned short)(a.y & 0xFFFF)) + bf2f((unsigned short)(b.y & 0xFFFF));
    r[3] = bf2f((unsigned short)(a.y >> 16))    + bf2f((unsigned short)(b.y >> 16));
    return r;
}

// ---------------------------------------------------------------------------
// Edge sort by destination row: histogram -> 1-block scan -> atomic scatter.
// After scatter: cursor[n] = END offset of node n's edge run; hist[n] = degree.
// ---------------------------------------------------------------------------
__global__ __launch_bounds__(256) void hist_kernel(
    const int* __restrict__ row, int* __restrict__ hist)
{
    const int e = blockIdx.x * 256 + threadIdx.x;
    if (e < N_EDGES_) atomicAdd(&hist[row[e]], 1);
}

__global__ __launch_bounds__(256) void scan_kernel(
    const int* __restrict__ hist, int* __restrict__ cursor)
{
    __shared__ int ssum[256];
    const int tid = threadIdx.x;
    const int chunk = (N_NODES_ + 255) / 256;
    const int base = tid * chunk;
    int s = 0;
    for (int i = 0; i < chunk; ++i) {
        const int idx = base + i;
        if (idx < N_NODES_) s += hist[idx];
    }
    ssum[tid] = s;
    __syncthreads();
    for (int off = 1; off < 256; off <<= 1) {
        const int t2 = (tid >= off) ? ssum[tid - off] : 0;
        __syncthreads();
        ssum[tid] += t2;
        __syncthreads();
    }
    int run = ssum[tid] - s;
    for (int i = 0; i < chunk; ++i) {
        const int idx = base + i;
        if (idx < N_NODES_) { cursor[idx] = run; run += hist[idx]; }
    }
}

__global__ __launch_bounds__(256) void scatter_kernel(
    const int* __restrict__ row, const int* __restrict__ col,
    int* __restrict__ cursor, int* __restrict__ row_s, int* __restrict__ col_s)
{
    const int e = blockIdx.x * 256 + threadIdx.x;
    if (e >= N_EDGES_) return;
    const int r = row[e];
    const int p = atomicAdd(&cursor[r], 1);
    row_s[p] = r;
    col_s[p] = col[e];
}

// ---------------------------------------------------------------------------
// Weight packing: fp32 [K][128] -> bf16 A-operand (W^T) fragment order.
// 256 blocks: 0..199 edge MLP | 200..207 atom_w | 208..247 node_w | 248..255 emb
// ---------------------------------------------------------------------------
__global__ __launch_bounds__(256) void pack_w_kernel(
    const float* __restrict__ edge_w0, const float* __restrict__ edge_w,
    const float* __restrict__ atom_w, const float* __restrict__ node_w,
    const float* __restrict__ edge_emb_w,
    unsigned short* __restrict__ Wp)
{
    const int bid = blockIdx.x;
    int Kb, t;
    const float* src;
    unsigned short* dst;
    if (bid < 200) {
        const int l = bid / 40, r = bid % 40, s = r / 8;
        t = r % 8;
        Kb = (s == 0) ? 12 : 4;
        src = (s == 0) ? edge_w0 + (size_t)l * 384 * 128
                       : edge_w + ((size_t)l * 4 + (s - 1)) * 128 * 128;
        dst = Wp + (size_t)l * 114688 + ((s == 0) ? 0 : (49152 + (s - 1) * 16384))
            + (size_t)t * Kb * 512;
    } else if (bid < 208) {
        t = bid - 200; Kb = 4; src = atom_w;
        dst = Wp + WP_ATOM + (size_t)t * Kb * 512;
    } else if (bid < 248) {
        const int l = (bid - 208) >> 3; t = (bid - 208) & 7; Kb = 4;
        src = node_w + (size_t)l * 128 * 128;
        dst = Wp + WP_NODE0 + (size_t)l * 16384 + (size_t)t * Kb * 512;
    } else {
        t = bid - 248; Kb = 1; src = edge_emb_w;
        dst = Wp + WP_EMB + (size_t)t * 512;
    }
    const int n = Kb * 512;
    for (int p = threadIdx.x; p < n; p += 256) {
        const int j = p & 7, lane = (p >> 3) & 63, kb = p >> 9;
        const int k  = kb * 32 + ((lane >> 4) << 3) + j;
        const int nn = t * 16 + (lane & 15);
        dst[p] = f2bf(src[(size_t)k * 128 + nn]);
    }
}

// ---------------------------------------------------------------------------
// Per-node stage-0 factorization:  Ur = h_node @ W0r + b0,  Uc = h_node @ W0c
// (bf16 out). Consumes kb 4..7 / 8..11 of the packed stage-0 slab; the edge
// kernel then only needs the h_edge (kb 0..3) MFMA + per-lane gathers of Ur/Uc.
// ---------------------------------------------------------------------------
__global__ __launch_bounds__(256, 4) void u_gemm_kernel(
    const unsigned short* __restrict__ h_node_bf,
    const unsigned short* __restrict__ Wp0, const float* __restrict__ b0,
    unsigned short* __restrict__ Ur, unsigned short* __restrict__ Uc, int N)
{
    __shared__ __align__(16) unsigned short B[64][136];
    const int tid  = threadIdx.x;
    const int lane = tid & 63;
    const int wv   = tid >> 6;
    const int n0   = blockIdx.x * 64;

    {
        const int t = tid >> 2, q = tid & 3;
        const int node = n0 + t;
#pragma unroll
        for (int i = 0; i < 4; ++i) {
            const int k8 = (q + 4 * i) << 3;
            short8 v = (short8){0,0,0,0,0,0,0,0};
            if (node < N) v = *(const short8*)&h_node_bf[(size_t)node * 128 + k8];
            *(short8*)&B[t][k8] = v;
        }
    }
    wave_lds_fence();

    const int lr = lane & 15, lg = lane >> 4;
    floatx4 accr[8], accc[8];
#pragma unroll
    for (int nt = 0; nt < 8; ++nt) {
        const float4 bv = *(const float4*)&b0[nt * 16 + lg * 4];
        accr[nt] = (floatx4){bv.x, bv.y, bv.z, bv.w};
        accc[nt] = (floatx4){0.f, 0.f, 0.f, 0.f};
    }
    const unsigned short* brow = &B[wv * 16 + lr][0];
#pragma unroll 2
    for (int kb = 0; kb < 4; ++kb) {
        const short8 mf = *(const short8*)(brow + kb * 32 + lg * 8);
#pragma unroll
        for (int nt = 0; nt < 8; ++nt) {
            const short8 wr = *(const short8*)(Wp0 + ((size_t)(nt * 12 + 4 + kb) * 64 + lane) * 8);
            const short8 wc = *(const short8*)(Wp0 + ((size_t)(nt * 12 + 8 + kb) * 64 + lane) * 8);
            accr[nt] = __builtin_amdgcn_mfma_f32_16x16x32_bf16(wr, mf, accr[nt], 0, 0, 0);
            accc[nt] = __builtin_amdgcn_mfma_f32_16x16x32_bf16(wc, mf, accc[nt], 0, 0, 0);
        }
    }
    const int node = n0 + wv * 16 + lr;
    if (node < N) {
        unsigned short* rrow = Ur + (size_t)node * 128;
        unsigned short* crow = Uc + (size_t)node * 128;
#pragma unroll
        for (int nt = 0; nt < 8; ++nt) {
            uint2 o;
            o.x = f2bf_pk(accr[nt][0], accr[nt][1]);
            o.y = f2bf_pk(accr[nt][2], accr[nt][3]);
            *(uint2*)(rrow + nt * 16 + lg * 4) = o;
            o.x = f2bf_pk(accc[nt][0], accc[nt][1]);
            o.y = f2bf_pk(accc[nt][2], accc[nt][3]);
            *(uint2*)(crow + nt * 16 + lg * 4) = o;
        }
    }
}

// ---------------------------------------------------------------------------
// Sorted-edge MFMA edge MLP — round-15: wave-independent, barrier-free.
//  - each wave owns 32 edges x all 128 features: stage outputs never cross
//    waves -> ZERO __syncthreads, ZERO LDS.
//  - stage-to-stage C-layout -> B-layout feature redistribution done in-wave
//    with permlane32_swap + permlane16_swap (4 VALU ops per k-block).
//  - stage-0 B-frags loaded straight from h_edge; acc seeded from Ur/Uc
//    per-lane gathers (b0 folded in Ur); epilogue re-reads residual (L2-hot)
//    and stores coalesced 16B/lane.
// ---------------------------------------------------------------------------
__global__ __launch_bounds__(256, 3) void edge_mlp_csr_kernel(
    unsigned short* __restrict__ h_edge,
    const unsigned short* __restrict__ Ur, const unsigned short* __restrict__ Uc,
    const int* __restrict__ row_s, const int* __restrict__ col_s,
    const unsigned short* __restrict__ Wp, const float* __restrict__ bh)
{
    const int tid  = threadIdx.x;
    const int lane = tid & 63;
    const int lr   = lane & 15;
    const int lg   = lane >> 4;
    const int e0   = blockIdx.x * 128 + (tid >> 6) * 32;

    const int eA = e0 + lr, eB = eA + 16;
    const int ridA = row_s[eA], cidA = col_s[eA];
    const int ridB = row_s[eB], cidB = col_s[eB];

    // stage-0 B-fragments straight from h_edge (16B contiguous per lane)
    short8 bf[2][4];
#pragma unroll
    for (int kb = 0; kb < 4; ++kb) {
        bf[0][kb] = *(const short8*)&h_edge[(size_t)eA * 128 + kb * 32 + lg * 8];
        bf[1][kb] = *(const short8*)&h_edge[(size_t)eB * 128 + kb * 32 + lg * 8];
    }

    // acc init = Ur[row] + Uc[col] in C-fragment layout (b0 folded into Ur)
    floatx4 acc[2][8];
#pragma unroll
    for (int nt = 0; nt < 8; ++nt) {
        const int fo = nt * 16 + lg * 4;
        const uint2 rA = *(const uint2*)(Ur + (size_t)ridA * 128 + fo);
        const uint2 cA = *(const uint2*)(Uc + (size_t)cidA * 128 + fo);
        const uint2 rB = *(const uint2*)(Ur + (size_t)ridB * 128 + fo);
        const uint2 cB = *(const uint2*)(Uc + (size_t)cidB * 128 + fo);
        acc[0][nt] = upair_sum(rA, cA);
        acc[1][nt] = upair_sum(rB, cB);
    }

    // 5 MLP stages, all in registers
#pragma unroll
    for (int s = 0; s < 5; ++s) {
        const unsigned short* __restrict__ Ws =
            (s == 0) ? Wp : (Wp + 49152 + (size_t)(s - 1) * 16384);
        const int nst = (s == 0) ? 12 : 4;
#pragma unroll
        for (int nt = 0; nt < 8; ++nt) {
#pragma unroll
            for (int kb = 0; kb < 4; ++kb) {
                const short8 wf = *(const short8*)(Ws + ((size_t)(nt * nst + kb) * 64 + lane) * 8);
                acc[0][nt] = __builtin_amdgcn_mfma_f32_16x16x32_bf16(wf, bf[0][kb], acc[0][nt], 0, 0, 0);
                acc[1][nt] = __builtin_amdgcn_mfma_f32_16x16x32_bf16(wf, bf[1][kb], acc[1][nt], 0, 0, 0);
            }
        }
        // silu -> bf16 pack -> in-wave exchange to next-stage B-fragments
        uint2 pk[2][8];
#pragma unroll
        for (int h = 0; h < 2; ++h)
#pragma unroll
            for (int nt = 0; nt < 8; ++nt) {
                pk[h][nt].x = f2bf_pk(silu_f(acc[h][nt][0]), silu_f(acc[h][nt][1]));
                pk[h][nt].y = f2bf_pk(silu_f(acc[h][nt][2]), silu_f(acc[h][nt][3]));
            }
#pragma unroll
        for (int h = 0; h < 2; ++h)
#pragma unroll
            for (int kb = 0; kb < 4; ++kb)
                bf[h][kb] = xchg_frag(pk[h][2 * kb], pk[h][2 * kb + 1]);

        if (s < 4) {
            const float* bias = bh + s * 128;
#pragma unroll
            for (int nt = 0; nt < 8; ++nt) {
                const float4 bv = *(const float4*)&bias[nt * 16 + lg * 4];
                acc[0][nt] = (floatx4){bv.x, bv.y, bv.z, bv.w};
                acc[1][nt] = acc[0][nt];
            }
        }
    }

    // epilogue: h_edge += m (stage-4 B-frags); residual re-read is L2-hot
#pragma unroll
    for (int h = 0; h < 2; ++h) {
        unsigned short* erow = h_edge + (size_t)((h == 0) ? eA : eB) * 128 + lg * 8;
#pragma unroll
        for (int kb = 0; kb < 4; ++kb) {
            const short8 ov = *(const short8*)(erow + kb * 32);
            const short8 mv = bf[h][kb];
            float v[8];
#pragma unroll
            for (int j = 0; j < 8; ++j)
                v[j] = bf2f((unsigned short)ov[j]) + bf2f((unsigned short)mv[j]);
            uint4 sv;
            sv.x = f2bf_pk(v[0], v[1]);
            sv.y = f2bf_pk(v[2], v[3]);
            sv.z = f2bf_pk(v[4], v[5]);
            sv.w = f2bf_pk(v[6], v[7]);
            *(uint4*)(erow + kb * 32) = sv;
        }
    }
}

// ---------------------------------------------------------------------------
// Fused CSR segment-sum + MFMA node update:
//   agg[n] = sum of h_edge rows in [cursor[n]-hist[n], cursor[n])  (fp32)
//   h_node[n] += silu(agg @ node_w + node_b)
// ---------------------------------------------------------------------------
__global__ __launch_bounds__(256, 4) void node_agg_gemm_kernel(
    const unsigned short* __restrict__ h_edge,
    const int* __restrict__ hist, const int* __restrict__ cur_end,
    const unsigned short* __restrict__ Wpm, const float* __restrict__ bias,
    unsigned short* __restrict__ h_node_bf, int N)
{
    __shared__ __align__(16) unsigned short B[64][136];
    const int tid  = threadIdx.x;
    const int lane = tid & 63;
    const int wv   = tid >> 6;
    const int n0   = blockIdx.x * 64;

    {
        const int t = tid >> 2, q = tid & 3;
        const int n = n0 + t;
        float a[32];
#pragma unroll
        for (int j = 0; j < 32; ++j) a[j] = 0.f;
        if (n < N) {
            const int e_end = cur_end[n];
            const int e_beg = e_end - hist[n];
            for (int e = e_beg; e < e_end; ++e) {
                const unsigned short* p = &h_edge[(size_t)e * 128 + q * 32];
#pragma unroll
                for (int g = 0; g < 4; ++g) {
                    const short8 v = *(const short8*)(p + g * 8);
#pragma unroll
                    for (int j = 0; j < 8; ++j)
                        a[g * 8 + j] += bf2f((unsigned short)v[j]);
                }
            }
        }
#pragma unroll
        for (int g = 0; g < 4; ++g) {
            uint4 pk;
            pk.x = f2bf_pk(a[g * 8 + 0], a[g * 8 + 1]);
            pk.y = f2bf_pk(a[g * 8 + 2], a[g * 8 + 3]);
            pk.z = f2bf_pk(a[g * 8 + 4], a[g * 8 + 5]);
            pk.w = f2bf_pk(a[g * 8 + 6], a[g * 8 + 7]);
            *(uint4*)&B[t][q * 32 + g * 8] = pk;
        }
    }
    wave_lds_fence();

    const int lr = lane & 15, lg = lane >> 4;
    floatx4 acc[8];
#pragma unroll
    for (int nt = 0; nt < 8; ++nt) {
        const float4 bv = *(const float4*)&bias[nt * 16 + lg * 4];
        acc[nt] = (floatx4){bv.x, bv.y, bv.z, bv.w};
    }
    const unsigned short* brow = &B[wv * 16 + lr][0];
#pragma unroll 2
    for (int kb = 0; kb < 4; ++kb) {
        const short8 mf = *(const short8*)(brow + kb * 32 + lg * 8);
#pragma unroll
        for (int nt = 0; nt < 8; ++nt) {
            const short8 wf = *(const short8*)(Wpm + ((size_t)(nt * 4 + kb) * 64 + lane) * 8);
            acc[nt] = __builtin_amdgcn_mfma_f32_16x16x32_bf16(wf, mf, acc[nt], 0, 0, 0);
        }
    }
    const int node = n0 + wv * 16 + lr;
    if (node < N) {
        unsigned short* drow = &h_node_bf[(size_t)node * 128];
#pragma unroll
        for (int nt = 0; nt < 8; ++nt) {
            float x0 = silu_f(acc[nt][0]), x1 = silu_f(acc[nt][1]);
            float x2 = silu_f(acc[nt][2]), x3 = silu_f(acc[nt][3]);
            unsigned short* p = drow + nt * 16 + lg * 4;
            const uint2 d = *(const uint2*)p;
            x0 += bf2f((unsigned short)(d.x & 0xFFFF));
            x1 += bf2f((unsigned short)(d.x >> 16));
            x2 += bf2f((unsigned short)(d.y & 0xFFFF));
            x3 += bf2f((unsigned short)(d.y >> 16));
            uint2 o;
            o.x = f2bf_pk(x0, x1);
            o.y = f2bf_pk(x2, x3);
            *(uint2*)p = o;
        }
    }
}

// ---------------------------------------------------------------------------
// MFMA row GEMM (atom embedding): dst = gather(src)[z] @ W + b, bf16 out.
// ---------------------------------------------------------------------------
__global__ __launch_bounds__(256, 4) void atom_gemm_mfma_kernel(
    const float* __restrict__ src, const int* __restrict__ gidx,
    const unsigned short* __restrict__ Wpm, const float* __restrict__ bias,
    unsigned short* __restrict__ dst, int N)
{
    __shared__ __align__(16) unsigned short B[64][136];
    const int tid  = threadIdx.x;
    const int lane = tid & 63;
    const int wv   = tid >> 6;
    const int n0   = blockIdx.x * 64;

    {
        const int t = tid >> 2, q = tid & 3;
        const int node = n0 + t;
        const float* srow = src;
        if (node < N) srow = &src[(size_t)gidx[node] * 128];
#pragma unroll
        for (int i = 0; i < 4; ++i) {
            const int k8 = (q + 4 * i) << 3;
            uint4 pk = make_uint4(0, 0, 0, 0);
            if (node < N) {
                const float4 f0 = *(const float4*)(srow + k8);
                const float4 f1 = *(const float4*)(srow + k8 + 4);
                pk.x = f2bf_pk(f0.x, f0.y);
                pk.y = f2bf_pk(f0.z, f0.w);
                pk.z = f2bf_pk(f1.x, f1.y);
                pk.w = f2bf_pk(f1.z, f1.w);
            }
            *(uint4*)&B[t][k8] = pk;
        }
    }
    wave_lds_fence();

    const int lr = lane & 15, lg = lane >> 4;
    floatx4 acc[8];
#pragma unroll
    for (int nt = 0; nt < 8; ++nt) {
        const float4 bv = *(const float4*)&bias[nt * 16 + lg * 4];
        acc[nt] = (floatx4){bv.x, bv.y, bv.z, bv.w};
    }
    const unsigned short* brow = &B[wv * 16 + lr][0];
#pragma unroll 2
    for (int kb = 0; kb < 4; ++kb) {
        const short8 mf = *(const short8*)(brow + kb * 32 + lg * 8);
#pragma unroll
        for (int nt = 0; nt < 8; ++nt) {
            const short8 wf = *(const short8*)(Wpm + ((size_t)(nt * 4 + kb) * 64 + lane) * 8);
            acc[nt] = __builtin_amdgcn_mfma_f32_16x16x32_bf16(wf, mf, acc[nt], 0, 0, 0);
        }
    }
    const int node = n0 + wv * 16 + lr;
    if (node < N) {
        unsigned short* drow = &dst[(size_t)node * 128];
#pragma unroll
        for (int nt = 0; nt < 8; ++nt) {
            uint2 o;
            o.x = f2bf_pk(acc[nt][0], acc[nt][1]);
            o.y = f2bf_pk(acc[nt][2], acc[nt][3]);
            *(uint2*)(drow + nt * 16 + lg * 4) = o;
        }
    }
}

// ---------------------------------------------------------------------------
// MFMA edge embedding: basis [64,32] bf16 in LDS, one K=32 MFMA pass.
// ---------------------------------------------------------------------------
__global__ __launch_bounds__(256, 4) void edge_embed_mfma_kernel(
    const float* __restrict__ pos, const int* __restrict__ row, const int* __restrict__ col,
    const unsigned short* __restrict__ Wpe, const float* __restrict__ bemb,
    unsigned short* __restrict__ h_edge)
{
    __shared__ __align__(16) unsigned short Bas[64][40];
    const int tid  = threadIdx.x;
    const int lane = tid & 63;
    const int wv   = tid >> 6;
    const int e0   = blockIdx.x * 64;

    {
        const int t = tid >> 2, q = tid & 3;
        const int rr = row[e0 + t], cc = col[e0 + t];
        const float dx = pos[rr * 3 + 0] - pos[cc * 3 + 0];
        const float dy = pos[rr * 3 + 1] - pos[cc * 3 + 1];
        const float dz = pos[rr * 3 + 2] - pos[cc * 3 + 2];
        const float d = sqrtf(dx * dx + dy * dy + dz * dz);
        const float invs = 32.0f / 5.0f;
        float e[8];
#pragma unroll
        for (int j = 0; j < 8; ++j) {
            const float mu = (float)(q * 8 + j) * (5.0f / 31.0f);
            const float tt = (d - mu) * invs;
            e[j] = __expf(-0.5f * tt * tt);
        }
        uint4 pk;
        pk.x = f2bf_pk(e[0], e[1]);
        pk.y = f2bf_pk(e[2], e[3]);
        pk.z = f2bf_pk(e[4], e[5]);
        pk.w = f2bf_pk(e[6], e[7]);
        *(uint4*)&Bas[t][q * 8] = pk;
    }
    wave_lds_fence();

    const int lr = lane & 15, lg = lane >> 4;
    floatx4 acc[8];
#pragma unroll
    for (int nt = 0; nt < 8; ++nt) {
        const float4 bv = *(const float4*)&bemb[nt * 16 + lg * 4];
        acc[nt] = (floatx4){bv.x, bv.y, bv.z, bv.w};
    }
    const short8 mf = *(const short8*)&Bas[wv * 16 + lr][lg * 8];
#pragma unroll
    for (int nt = 0; nt < 8; ++nt) {
        const short8 wf = *(const short8*)(Wpe + ((size_t)nt * 64 + lane) * 8);
        acc[nt] = __builtin_amdgcn_mfma_f32_16x16x32_bf16(wf, mf, acc[nt], 0, 0, 0);
    }
    unsigned short* erow = &h_edge[(size_t)(e0 + wv * 16 + lr) * 128];
#pragma unroll
    for (int nt = 0; nt < 8; ++nt) {
        uint2 o;
        o.x = f2bf_pk(acc[nt][0], acc[nt][1]);
        o.y = f2bf_pk(acc[nt][2], acc[nt][3]);
        *(uint2*)(erow + nt * 16 + lg * 4) = o;
    }
}

// ---------------------------------------------------------------------------
// Graph pooling (bf16 node state) + output head.
// ---------------------------------------------------------------------------
__global__ __launch_bounds__(128) void pool_kernel(
    const unsigned short* __restrict__ h_node_bf, const int* __restrict__ batch,
    float* __restrict__ sums, float* __restrict__ cnt, int N)
{
    __shared__ int bb[256];
    const int tid = threadIdx.x;
    const int n0 = blockIdx.x * 256;
    for (int idx = tid; idx < 256; idx += 128) {
        int n = n0 + idx;
        bb[idx] = (n < N) ? batch[n] : -1;
    }
    __syncthreads();
    int cur = bb[0];
    float run = 0.f, runc = 0.f;
    for (int i = 0; i < 256; ++i) {
        const int b = bb[i];
        if (b < 0) break;
        if (b != cur) {
            atomicAdd(&sums[(size_t)cur * 128 + tid], run);
            if (tid == 0) atomicAdd(&cnt[cur], runc);
            run = 0.f; runc = 0.f; cur = b;
        }
        run += bf2f(h_node_bf[(size_t)(n0 + i) * 128 + tid]);
        runc += 1.f;
    }
    atomicAdd(&sums[(size_t)cur * 128 + tid], run);
    if (tid == 0) atomicAdd(&cnt[cur], runc);
}

__global__ __launch_bounds__(256) void final_kernel(
    const float* __restrict__ sums, const float* __restrict__ cnt,
    const float* __restrict__ out_w, const float* __restrict__ out_b,
    float* __restrict__ out)
{
    const int g = threadIdx.x;
    const float c = fmaxf(cnt[g], 1.0f);
    float acc = 0.f;
    for (int jj = 0; jj < 128; ++jj) acc = fmaf(sums[(size_t)g * 128 + jj], out_w[jj], acc);
    out[g] = acc / c + out_b[0];
}

__global__ void zero_out_kernel(float* out, int n) {
    int i = blockIdx.x * 256 + threadIdx.x;
    if (i < n) out[i] = 0.f;
}

// ---------------------------------------------------------------------------

extern "C" void kernel_launch(void* const* d_in, const int* in_sizes, int n_in,
                              void* d_out, int out_size, void* d_ws, size_t ws_size,
                              hipStream_t stream)
{
    const int*   z          = (const int*)  d_in[0];
    const float* pos        = (const float*)d_in[1];
    const int*   batch      = (const int*)  d_in[2];
    const int*   eidx       = (const int*)  d_in[3];
    const float* atom_table = (const float*)d_in[4];
    const float* atom_w     = (const float*)d_in[5];
    const float* atom_b     = (const float*)d_in[6];
    const float* edge_emb_w = (const float*)d_in[7];
    const float* edge_emb_b = (const float*)d_in[8];
    const float* edge_w0    = (const float*)d_in[9];
    const float* edge_b0    = (const float*)d_in[10];
    const float* edge_w     = (const float*)d_in[11];
    const float* edge_b     = (const float*)d_in[12];
    const float* node_w     = (const float*)d_in[13];
    const float* node_b     = (const float*)d_in[14];
    const float* out_w      = (const float*)d_in[15];
    const float* out_b      = (const float*)d_in[16];
    const int* row = eidx;
    const int* col = eidx + N_EDGES_;

    // ws layout (identical footprint to round 10 — known to fit).
    // The former fp32 agg buffer (unused) now hosts Ur/Uc (bf16, 2x 12.8MB).
    float* aggb = (float*)d_ws;
    float* sums = aggb + (size_t)N_NODES_ * EMB;
    float* cnt  = sums + (size_t)N_GRAPH_ * EMB;
    unsigned short* h_node_bf = (unsigned short*)(cnt + N_GRAPH_);
    unsigned short* h_edge    = h_node_bf + (size_t)N_NODES_ * EMB;
    unsigned short* Wp        = h_edge + (size_t)N_EDGES_ * EMB;
    int* hist   = (int*)(Wp + WP_TOTAL);
    int* cursor = hist + N_NODES_;
    int* row_s  = cursor + N_NODES_;
    int* col_s  = row_s + N_EDGES_;

    unsigned short* Ur = (unsigned short*)aggb;
    unsigned short* Uc = Ur + (size_t)N_NODES_ * EMB;

    const size_t need = ((size_t)(N_NODES_ * EMB + N_GRAPH_ * EMB + N_GRAPH_)) * 4
                      + ((size_t)N_NODES_ * EMB + (size_t)N_EDGES_ * EMB + (size_t)WP_TOTAL) * 2
                      + ((size_t)N_NODES_ * 2 + (size_t)N_EDGES_ * 2) * 4;

    if (ws_size < need) {
        zero_out_kernel<<<1, 256, 0, stream>>>((float*)d_out, N_GRAPH_);
        return;
    }

    const int grid_rows64 = (N_NODES_ + 63) / 64;   // 782

    (void)hipMemsetAsync(hist, 0, N_NODES_ * sizeof(int), stream);
    hist_kernel<<<(N_EDGES_ + 255) / 256, 256, 0, stream>>>(row, hist);
    scan_kernel<<<1, 256, 0, stream>>>(hist, cursor);
    scatter_kernel<<<(N_EDGES_ + 255) / 256, 256, 0, stream>>>(row, col, cursor, row_s, col_s);
    // post-scatter: cursor[n] = end offset, hist[n] = degree

    pack_w_kernel<<<256, 256, 0, stream>>>(edge_w0, edge_w, atom_w, node_w, edge_emb_w, Wp);

    atom_gemm_mfma_kernel<<<grid_rows64, 256, 0, stream>>>(
        atom_table, z, Wp + WP_ATOM, atom_b, h_node_bf, N_NODES_);
    edge_embed_mfma_kernel<<<N_EDGES_ / 64, 256, 0, stream>>>(
        pos, row_s, col_s, Wp + WP_EMB, edge_emb_b, h_edge);

    for (int l = 0; l < NLAYER_; ++l) {
        u_gemm_kernel<<<grid_rows64, 256, 0, stream>>>(
            h_node_bf, Wp + (size_t)l * 114688, edge_b0 + (size_t)l * 128,
            Ur, Uc, N_NODES_);
        edge_mlp_csr_kernel<<<N_EDGES_ / 128, 256, 0, stream>>>(
            h_edge, Ur, Uc, row_s, col_s,
            Wp + (size_t)l * 114688,
            edge_b + (size_t)l * 4 * 128);
        node_agg_gemm_kernel<<<grid_rows64, 256, 0, stream>>>(
            h_edge, hist, cursor,
            Wp + WP_NODE0 + (size_t)l * 16384, node_b + (size_t)l * 128,
            h_node_bf, N_NODES_);
    }

    (void)hipMemsetAsync(sums, 0, ((size_t)N_GRAPH_ * EMB + N_GRAPH_) * sizeof(float), stream);
    pool_kernel<<<(N_NODES_ + 255) / 256, 128, 0, stream>>>(h_node_bf, batch, sums, cnt, N_NODES_);
    final_kernel<<<1, 256, 0, stream>>>(sums, cnt, out_w, out_b, (float*)d_out);
}

// Round 5
// 2996.596 us; speedup vs baseline: 1.2168x; 1.2168x over previous
//
#include <hip/hip_runtime.h>

#define EMB      128
#define N_NODES_ 50000
#define N_EDGES_ 800000
#define N_GRAPH_ 256
#define NLAYER_  5

// packed-weight layout offsets (ushort elements)
#define WP_ATOM  573440
#define WP_NODE0 589824
#define WP_EMB   671744
#define WP_TOTAL 675840

typedef short short8 __attribute__((ext_vector_type(8)));
typedef float floatx4 __attribute__((ext_vector_type(4)));
typedef unsigned uintx2 __attribute__((ext_vector_type(2)));

__device__ __forceinline__ float silu_f(float x) {
    return __fdividef(x, 1.0f + __expf(-x));
}
__device__ __forceinline__ float bf2f(unsigned short h) {
    return __uint_as_float(((unsigned)h) << 16);
}
__device__ __forceinline__ unsigned short f2bf(float f) {
    unsigned u = __float_as_uint(f);
    unsigned r = 0x7FFFu + ((u >> 16) & 1u);
    return (unsigned short)((u + r) >> 16);
}

#if defined(__has_builtin)
#if __has_builtin(__builtin_amdgcn_cvt_pk_bf16_f32)
#define HAVE_PK_BF16 1
#endif
#if __has_builtin(__builtin_amdgcn_permlane16_swap) && __has_builtin(__builtin_amdgcn_permlane32_swap)
#define HAVE_PERMLANE_SWAP 1
#endif
#endif

#ifdef HAVE_PK_BF16
typedef __bf16 bf16x2 __attribute__((ext_vector_type(2)));
__device__ __forceinline__ unsigned f2bf_pk(float a, float b) {
    bf16x2 v = __builtin_amdgcn_cvt_pk_bf16_f32(a, b);
    unsigned u;
    __builtin_memcpy(&u, &v, 4);
    return u;
}
#else
__device__ __forceinline__ unsigned f2bf_pk(float a, float b) {
    return (unsigned)f2bf(a) | ((unsigned)f2bf(b) << 16);
}
#endif

// wave-local LDS ordering (validated: correctness held)
__device__ __forceinline__ void wave_lds_fence() {
    __builtin_amdgcn_fence(__ATOMIC_ACQ_REL, "wavefront");
    __builtin_amdgcn_wave_barrier();
}

// async global -> LDS, 16B per lane. LDS dest = uniform base + lane*16.
__device__ __forceinline__ void gload_lds16(const unsigned short* g, unsigned short* l) {
    __builtin_amdgcn_global_load_lds(
        (const __attribute__((address_space(1))) void*)g,
        (__attribute__((address_space(3))) void*)l,
        16, 0, 0);
}

// ---------------------------------------------------------------------------
// In-wave 16-lane-row exchanges (verified numerically exact in round 4).
// Convert MFMA C-fragment uint2 packs into next-GEMM B-fragments in-register.
// Exchanges cross lg-groups only (lane&15 preserved -> no row/node mixing).
// ---------------------------------------------------------------------------
__device__ __forceinline__ void swap32(unsigned &a, unsigned &b) {
#ifdef HAVE_PERMLANE_SWAP
    uintx2 r = __builtin_amdgcn_permlane32_swap(a, b, false, false);
    a = r.x; b = r.y;
#else
    const int lane = (int)(threadIdx.x & 63);
    const int idx = (lane ^ 32) << 2;
    const unsigned ta = (unsigned)__builtin_amdgcn_ds_bpermute(idx, (int)a);
    const unsigned tb = (unsigned)__builtin_amdgcn_ds_bpermute(idx, (int)b);
    const bool hi = lane >= 32;
    const unsigned na = hi ? tb : a;
    const unsigned nb = hi ? b : ta;
    a = na; b = nb;
#endif
}
__device__ __forceinline__ void swap16(unsigned &a, unsigned &b) {
#ifdef HAVE_PERMLANE_SWAP
    uintx2 r = __builtin_amdgcn_permlane16_swap(a, b, false, false);
    a = r.x; b = r.y;
#else
    const unsigned ta = (unsigned)__builtin_amdgcn_ds_swizzle((int)a, 0x401F); // lane^16
    const unsigned tb = (unsigned)__builtin_amdgcn_ds_swizzle((int)b, 0x401F);
    const bool odd = ((threadIdx.x >> 4) & 1) != 0;
    const unsigned na = odd ? tb : a;
    const unsigned nb = odd ? b : ta;
    a = na; b = nb;
#endif
}

// C-frag packs of n-tiles (2kb, 2kb+1) -> B-fragment short8 for k-block kb.
__device__ __forceinline__ short8 xchg_frag(uint2 pkE, uint2 pkO) {
    unsigned a0 = pkE.x, b0 = pkO.x;
    unsigned a1 = pkE.y, b1 = pkO.y;
    swap32(a0, b0); swap16(a0, b0);
    swap32(a1, b1); swap16(a1, b1);
    union { short8 s; unsigned u[4]; } r;
    r.u[0] = a0; r.u[1] = a1; r.u[2] = b0; r.u[3] = b1;
    return r.s;
}

__device__ __forceinline__ floatx4 upair_sum(uint2 a, uint2 b) {
    floatx4 r;
    r[0] = bf2f((unsigned short)(a.x & 0xFFFF)) + bf2f((unsigned short)(b.x & 0xFFFF));
    r[1] = bf2f((unsigned short)(a.x >> 16))    + bf2f((unsigned short)(b.x >> 16));
    r[2] = bf2f((unsigned short)(a.y & 0xFFFF)) + bf2f((unsigned short)(b.y & 0xFFFF));
    r[3] = bf2f((unsigned short)(a.y >> 16))    + bf2f((unsigned short)(b.y >> 16));
    return r;
}

// ---------------------------------------------------------------------------
// Edge sort by destination row: histogram -> 1-block scan -> atomic scatter.
// ---------------------------------------------------------------------------
__global__ __launch_bounds__(256) void hist_kernel(
    const int* __restrict__ row, int* __restrict__ hist)
{
    const int e = blockIdx.x * 256 + threadIdx.x;
    if (e < N_EDGES_) atomicAdd(&hist[row[e]], 1);
}

__global__ __launch_bounds__(256) void scan_kernel(
    const int* __restrict__ hist, int* __restrict__ cursor)
{
    __shared__ int ssum[256];
    const int tid = threadIdx.x;
    const int chunk = (N_NODES_ + 255) / 256;
    const int base = tid * chunk;
    int s = 0;
    for (int i = 0; i < chunk; ++i) {
        const int idx = base + i;
        if (idx < N_NODES_) s += hist[idx];
    }
    ssum[tid] = s;
    __syncthreads();
    for (int off = 1; off < 256; off <<= 1) {
        const int t2 = (tid >= off) ? ssum[tid - off] : 0;
        __syncthreads();
        ssum[tid] += t2;
        __syncthreads();
    }
    int run = ssum[tid] - s;
    for (int i = 0; i < chunk; ++i) {
        const int idx = base + i;
        if (idx < N_NODES_) { cursor[idx] = run; run += hist[idx]; }
    }
}

__global__ __launch_bounds__(256) void scatter_kernel(
    const int* __restrict__ row, const int* __restrict__ col,
    int* __restrict__ cursor, int* __restrict__ row_s, int* __restrict__ col_s)
{
    const int e = blockIdx.x * 256 + threadIdx.x;
    if (e >= N_EDGES_) return;
    const int r = row[e];
    const int p = atomicAdd(&cursor[r], 1);
    row_s[p] = r;
    col_s[p] = col[e];
}

// ---------------------------------------------------------------------------
// Weight packing: fp32 [K][128] -> bf16 A-operand (W^T) fragment order.
// ---------------------------------------------------------------------------
__global__ __launch_bounds__(256) void pack_w_kernel(
    const float* __restrict__ edge_w0, const float* __restrict__ edge_w,
    const float* __restrict__ atom_w, const float* __restrict__ node_w,
    const float* __restrict__ edge_emb_w,
    unsigned short* __restrict__ Wp)
{
    const int bid = blockIdx.x;
    int Kb, t;
    const float* src;
    unsigned short* dst;
    if (bid < 200) {
        const int l = bid / 40, r = bid % 40, s = r / 8;
        t = r % 8;
        Kb = (s == 0) ? 12 : 4;
        src = (s == 0) ? edge_w0 + (size_t)l * 384 * 128
                       : edge_w + ((size_t)l * 4 + (s - 1)) * 128 * 128;
        dst = Wp + (size_t)l * 114688 + ((s == 0) ? 0 : (49152 + (s - 1) * 16384))
            + (size_t)t * Kb * 512;
    } else if (bid < 208) {
        t = bid - 200; Kb = 4; src = atom_w;
        dst = Wp + WP_ATOM + (size_t)t * Kb * 512;
    } else if (bid < 248) {
        const int l = (bid - 208) >> 3; t = (bid - 208) & 7; Kb = 4;
        src = node_w + (size_t)l * 128 * 128;
        dst = Wp + WP_NODE0 + (size_t)l * 16384 + (size_t)t * Kb * 512;
    } else {
        t = bid - 248; Kb = 1; src = edge_emb_w;
        dst = Wp + WP_EMB + (size_t)t * 512;
    }
    const int n = Kb * 512;
    for (int p = threadIdx.x; p < n; p += 256) {
        const int j = p & 7, lane = (p >> 3) & 63, kb = p >> 9;
        const int k  = kb * 32 + ((lane >> 4) << 3) + j;
        const int nn = t * 16 + (lane & 15);
        dst[p] = f2bf(src[(size_t)k * 128 + nn]);
    }
}

// ---------------------------------------------------------------------------
// Sorted-edge MFMA edge MLP — round-16: 2-wave / 32-edge / 16 KB blocks.
// Same per-wave instruction mix as the round-3 kernel (32 MFMA + 32 silu +
// 8 LDS writes per stage) but: barrier domain = 2 waves, LDS 16 KB ->
// 10 resident blocks/CU, 25000 independent blocks for latency hiding.
// Wave wv owns n-tiles 4wv..4wv+3 (64 output cols); block owns 32 edges.
// ---------------------------------------------------------------------------
__global__ __launch_bounds__(128, 5) void edge_mlp_csr_kernel(
    unsigned short* __restrict__ h_edge,
    const unsigned short* __restrict__ Ur, const unsigned short* __restrict__ Uc,
    const int* __restrict__ row_s, const int* __restrict__ col_s,
    const unsigned short* __restrict__ Wp, const float* __restrict__ bh)
{
    __shared__ __align__(16) unsigned short Xs[4096];   // 32 x 128, 8 KB
    __shared__ __align__(16) unsigned short Ys[4096];   // 8 KB

    const int tid  = threadIdx.x;
    const int lane = tid & 63;
    const int wv   = tid >> 6;          // 0..1
    const int lr   = lane & 15;
    const int lg   = lane >> 4;
    const int e0   = blockIdx.x * 32;
    const int ntb  = 4 * wv;            // wave's first n-tile

    // async stage: Xs <- h_edge rows [0,32); wave wv stages rows [16wv,16wv+16)
    // chunk-swizzled source (slot c holds chunk c^(r&7)), linear LDS dest.
    const int srow = 16 * wv + lg;
#pragma unroll
    for (int j = 0; j < 4; ++j) {
        const int r = srow + 4 * j;
        const int c = lr ^ (r & 7);
        gload_lds16(h_edge + (size_t)(e0 + r) * 128 + c * 8,
                    &Xs[(16 * wv + 4 * j) * 128]);
    }

    int rid[2], cid[2];
#pragma unroll
    for (int et = 0; et < 2; ++et) {
        const int e = e0 + et * 16 + lr;
        rid[et] = row_s[e];
        cid[et] = col_s[e];
    }

    // acc seed = Ur[row] + Uc[col] (b0 folded into Ur), C-fragment layout
    floatx4 acc[2][4];
    {
        uint2 gr[2][4], gc[2][4];
#pragma unroll
        for (int et = 0; et < 2; ++et)
#pragma unroll
            for (int n = 0; n < 4; ++n) {
                const int fo = (ntb + n) * 16 + lg * 4;
                gr[et][n] = *(const uint2*)(Ur + (size_t)rid[et] * 128 + fo);
                gc[et][n] = *(const uint2*)(Uc + (size_t)cid[et] * 128 + fo);
            }
#pragma unroll
        for (int et = 0; et < 2; ++et)
#pragma unroll
            for (int n = 0; n < 4; ++n)
                acc[et][n] = upair_sum(gr[et][n], gc[et][n]);
    }

    asm volatile("s_waitcnt vmcnt(0)" ::: "memory");
    __syncthreads();

    short8 he_reg[4];
    const int t_ = tid >> 2, q_ = tid & 3;   // epilogue ownership: row t_, chunks q_+4i

    // ---- 5 stages: s0 X->Y, s1 Y->X, s2 X->Y, s3 Y->X, s4 X->Y ------------
#pragma unroll 1
    for (int s = 0; s < 5; ++s) {
        const unsigned short* __restrict__ bin = (s & 1) ? Ys : Xs;
        unsigned short* __restrict__ bout      = (s & 1) ? Xs : Ys;
        const unsigned short* __restrict__ Ws =
            (s == 0) ? Wp : (Wp + 49152 + (size_t)(s - 1) * 16384);
        const int nst = (s == 0) ? 12 : 4;

        if (s >= 1) {
            const float* bias = bh + (size_t)(s - 1) * 128;
#pragma unroll
            for (int n = 0; n < 4; ++n) {
                const float4 bv = *(const float4*)&bias[(ntb + n) * 16 + lg * 4];
                acc[0][n] = (floatx4){bv.x, bv.y, bv.z, bv.w};
                acc[1][n] = acc[0][n];
            }
        }

#pragma unroll 2
        for (int kk = 0; kk < 4; ++kk) {
            short8 wf[4];
#pragma unroll
            for (int n = 0; n < 4; ++n)
                wf[n] = *(const short8*)(Ws + ((size_t)((ntb + n) * nst + kk) * 64 + lane) * 8);
#pragma unroll
            for (int et = 0; et < 2; ++et) {
                const int r = et * 16 + lr;
                const short8 mf = *(const short8*)&bin[r * 128 + (((kk * 4 + lg) ^ (r & 7)) << 3)];
#pragma unroll
                for (int n = 0; n < 4; ++n)
                    acc[et][n] = __builtin_amdgcn_mfma_f32_16x16x32_bf16(wf[n], mf, acc[et][n], 0, 0, 0);
            }
        }

        // silu -> bf16 -> swizzled LDS write (wave-private 64-col region)
#pragma unroll
        for (int et = 0; et < 2; ++et) {
            const int r = et * 16 + lr;
#pragma unroll
            for (int n = 0; n < 4; ++n) {
                uint2 p;
                p.x = f2bf_pk(silu_f(acc[et][n][0]), silu_f(acc[et][n][1]));
                p.y = f2bf_pk(silu_f(acc[et][n][2]), silu_f(acc[et][n][3]));
                const int c = (2 * (ntb + n) + (lg >> 1)) ^ (r & 7);
                *(uint2*)&bout[r * 128 + c * 8 + (lg & 1) * 4] = p;
            }
        }

        if (s == 0) {
            // residual copy from Xs (intact until stage 1 writes it, which is
            // separated from this read by the barrier below)
#pragma unroll
            for (int i = 0; i < 4; ++i) {
                const int ch = q_ + 4 * i;
                he_reg[i] = *(const short8*)&Xs[t_ * 128 + ((ch ^ (t_ & 7)) << 3)];
            }
        }
        __syncthreads();
    }

    // ---- epilogue: h_edge = he_reg + m (final m in Ys); 16B coalesced -----
#pragma unroll
    for (int i = 0; i < 4; ++i) {
        const int ch = q_ + 4 * i;
        const short8 mv = *(const short8*)&Ys[t_ * 128 + ((ch ^ (t_ & 7)) << 3)];
        const short8 ov = he_reg[i];
        float v[8];
#pragma unroll
        for (int j = 0; j < 8; ++j)
            v[j] = bf2f((unsigned short)ov[j]) + bf2f((unsigned short)mv[j]);
        uint4 sv;
        sv.x = f2bf_pk(v[0], v[1]);
        sv.y = f2bf_pk(v[2], v[3]);
        sv.z = f2bf_pk(v[4], v[5]);
        sv.w = f2bf_pk(v[6], v[7]);
        *(uint4*)(h_edge + (size_t)(e0 + t_) * 128 + ch * 8) = sv;
    }
}

// ---------------------------------------------------------------------------
// Fused CSR segment-sum + MFMA node update + NEXT-LAYER U production:
//   agg[n] = sum of h_edge rows in CSR run (fp32)
//   h_node[n] += silu(agg @ node_w + node_b)
//   if (Wp0n): Ur[n] = h_node_new @ W0r + b0n ; Uc[n] = h_node_new @ W0c
// U computed in-register from the freshly packed bf16 h_node values via
// xchg_frag (identical numerics to re-reading h_node_bf).
// ---------------------------------------------------------------------------
__global__ __launch_bounds__(256, 3) void node_agg_gemm_kernel(
    const unsigned short* __restrict__ h_edge,
    const int* __restrict__ hist, const int* __restrict__ cur_end,
    const unsigned short* __restrict__ Wpm, const float* __restrict__ bias,
    unsigned short* __restrict__ h_node_bf, int N,
    const unsigned short* __restrict__ Wp0n, const float* __restrict__ b0n,
    unsigned short* __restrict__ Ur, unsigned short* __restrict__ Uc)
{
    __shared__ __align__(16) unsigned short B[64][136];
    const int tid  = threadIdx.x;
    const int lane = tid & 63;
    const int wv   = tid >> 6;
    const int n0   = blockIdx.x * 64;

    {
        const int t = tid >> 2, q = tid & 3;
        const int n = n0 + t;
        float a[32];
#pragma unroll
        for (int j = 0; j < 32; ++j) a[j] = 0.f;
        if (n < N) {
            const int e_end = cur_end[n];
            const int e_beg = e_end - hist[n];
            for (int e = e_beg; e < e_end; ++e) {
                const unsigned short* p = &h_edge[(size_t)e * 128 + q * 32];
#pragma unroll
                for (int g = 0; g < 4; ++g) {
                    const short8 v = *(const short8*)(p + g * 8);
#pragma unroll
                    for (int j = 0; j < 8; ++j)
                        a[g * 8 + j] += bf2f((unsigned short)v[j]);
                }
            }
        }
#pragma unroll
        for (int g = 0; g < 4; ++g) {
            uint4 pk;
            pk.x = f2bf_pk(a[g * 8 + 0], a[g * 8 + 1]);
            pk.y = f2bf_pk(a[g * 8 + 2], a[g * 8 + 3]);
            pk.z = f2bf_pk(a[g * 8 + 4], a[g * 8 + 5]);
            pk.w = f2bf_pk(a[g * 8 + 6], a[g * 8 + 7]);
            *(uint4*)&B[t][q * 32 + g * 8] = pk;
        }
    }
    wave_lds_fence();

    const int lr = lane & 15, lg = lane >> 4;
    floatx4 acc[8];
#pragma unroll
    for (int nt = 0; nt < 8; ++nt) {
        const float4 bv = *(const float4*)&bias[nt * 16 + lg * 4];
        acc[nt] = (floatx4){bv.x, bv.y, bv.z, bv.w};
    }
    const unsigned short* brow = &B[wv * 16 + lr][0];
#pragma unroll 2
    for (int kb = 0; kb < 4; ++kb) {
        const short8 mf = *(const short8*)(brow + kb * 32 + lg * 8);
#pragma unroll
        for (int nt = 0; nt < 8; ++nt) {
            const short8 wf = *(const short8*)(Wpm + ((size_t)(nt * 4 + kb) * 64 + lane) * 8);
            acc[nt] = __builtin_amdgcn_mfma_f32_16x16x32_bf16(wf, mf, acc[nt], 0, 0, 0);
        }
    }
    const int node = n0 + wv * 16 + lr;
    unsigned short* drow = &h_node_bf[(size_t)node * 128];

    uint2 o[8];
#pragma unroll
    for (int nt = 0; nt < 8; ++nt) {
        float x0 = silu_f(acc[nt][0]), x1 = silu_f(acc[nt][1]);
        float x2 = silu_f(acc[nt][2]), x3 = silu_f(acc[nt][3]);
        if (node < N) {
            const uint2 d = *(const uint2*)(drow + nt * 16 + lg * 4);
            x0 += bf2f((unsigned short)(d.x & 0xFFFF));
            x1 += bf2f((unsigned short)(d.x >> 16));
            x2 += bf2f((unsigned short)(d.y & 0xFFFF));
            x3 += bf2f((unsigned short)(d.y >> 16));
        }
        o[nt].x = f2bf_pk(x0, x1);
        o[nt].y = f2bf_pk(x2, x3);
    }
    if (node < N) {
#pragma unroll
        for (int nt = 0; nt < 8; ++nt)
            *(uint2*)(drow + nt * 16 + lg * 4) = o[nt];
    }

    if (Wp0n) {
        // C-frags -> B-frags in-register (lane&15 = node, preserved by xchg)
        short8 bf[4];
#pragma unroll
        for (int kb = 0; kb < 4; ++kb)
            bf[kb] = xchg_frag(o[2 * kb], o[2 * kb + 1]);

        floatx4 au[8];
#pragma unroll
        for (int nt = 0; nt < 8; ++nt) {
            const float4 bv = *(const float4*)&b0n[nt * 16 + lg * 4];
            au[nt] = (floatx4){bv.x, bv.y, bv.z, bv.w};
        }
#pragma unroll 2
        for (int kb = 0; kb < 4; ++kb) {
#pragma unroll
            for (int nt = 0; nt < 8; ++nt) {
                const short8 wr = *(const short8*)(Wp0n + ((size_t)(nt * 12 + 4 + kb) * 64 + lane) * 8);
                au[nt] = __builtin_amdgcn_mfma_f32_16x16x32_bf16(wr, bf[kb], au[nt], 0, 0, 0);
            }
        }
        if (node < N) {
            unsigned short* rrow = Ur + (size_t)node * 128;
#pragma unroll
            for (int nt = 0; nt < 8; ++nt) {
                uint2 u;
                u.x = f2bf_pk(au[nt][0], au[nt][1]);
                u.y = f2bf_pk(au[nt][2], au[nt][3]);
                *(uint2*)(rrow + nt * 16 + lg * 4) = u;
            }
        }
#pragma unroll
        for (int nt = 0; nt < 8; ++nt)
            au[nt] = (floatx4){0.f, 0.f, 0.f, 0.f};
#pragma unroll 2
        for (int kb = 0; kb < 4; ++kb) {
#pragma unroll
            for (int nt = 0; nt < 8; ++nt) {
                const short8 wc = *(const short8*)(Wp0n + ((size_t)(nt * 12 + 8 + kb) * 64 + lane) * 8);
                au[nt] = __builtin_amdgcn_mfma_f32_16x16x32_bf16(wc, bf[kb], au[nt], 0, 0, 0);
            }
        }
        if (node < N) {
            unsigned short* crow = Uc + (size_t)node * 128;
#pragma unroll
            for (int nt = 0; nt < 8; ++nt) {
                uint2 u;
                u.x = f2bf_pk(au[nt][0], au[nt][1]);
                u.y = f2bf_pk(au[nt][2], au[nt][3]);
                *(uint2*)(crow + nt * 16 + lg * 4) = u;
            }
        }
    }
}

// ---------------------------------------------------------------------------
// MFMA row GEMM (atom embedding) + layer-0 U production (same fusion).
// ---------------------------------------------------------------------------
__global__ __launch_bounds__(256, 3) void atom_gemm_mfma_kernel(
    const float* __restrict__ src, const int* __restrict__ gidx,
    const unsigned short* __restrict__ Wpm, const float* __restrict__ bias,
    unsigned short* __restrict__ dst, int N,
    const unsigned short* __restrict__ Wp0n, const float* __restrict__ b0n,
    unsigned short* __restrict__ Ur, unsigned short* __restrict__ Uc)
{
    __shared__ __align__(16) unsigned short B[64][136];
    const int tid  = threadIdx.x;
    const int lane = tid & 63;
    const int wv   = tid >> 6;
    const int n0   = blockIdx.x * 64;

    {
        const int t = tid >> 2, q = tid & 3;
        const int node = n0 + t;
        const float* srow = src;
        if (node < N) srow = &src[(size_t)gidx[node] * 128];
#pragma unroll
        for (int i = 0; i < 4; ++i) {
            const int k8 = (q + 4 * i) << 3;
            uint4 pk = make_uint4(0, 0, 0, 0);
            if (node < N) {
                const float4 f0 = *(const float4*)(srow + k8);
                const float4 f1 = *(const float4*)(srow + k8 + 4);
                pk.x = f2bf_pk(f0.x, f0.y);
                pk.y = f2bf_pk(f0.z, f0.w);
                pk.z = f2bf_pk(f1.x, f1.y);
                pk.w = f2bf_pk(f1.z, f1.w);
            }
            *(uint4*)&B[t][k8] = pk;
        }
    }
    wave_lds_fence();

    const int lr = lane & 15, lg = lane >> 4;
    floatx4 acc[8];
#pragma unroll
    for (int nt = 0; nt < 8; ++nt) {
        const float4 bv = *(const float4*)&bias[nt * 16 + lg * 4];
        acc[nt] = (floatx4){bv.x, bv.y, bv.z, bv.w};
    }
    const unsigned short* brow = &B[wv * 16 + lr][0];
#pragma unroll 2
    for (int kb = 0; kb < 4; ++kb) {
        const short8 mf = *(const short8*)(brow + kb * 32 + lg * 8);
#pragma unroll
        for (int nt = 0; nt < 8; ++nt) {
            const short8 wf = *(const short8*)(Wpm + ((size_t)(nt * 4 + kb) * 64 + lane) * 8);
            acc[nt] = __builtin_amdgcn_mfma_f32_16x16x32_bf16(wf, mf, acc[nt], 0, 0, 0);
        }
    }
    const int node = n0 + wv * 16 + lr;
    uint2 o[8];
#pragma unroll
    for (int nt = 0; nt < 8; ++nt) {
        o[nt].x = f2bf_pk(acc[nt][0], acc[nt][1]);
        o[nt].y = f2bf_pk(acc[nt][2], acc[nt][3]);
    }
    if (node < N) {
        unsigned short* drow = &dst[(size_t)node * 128];
#pragma unroll
        for (int nt = 0; nt < 8; ++nt)
            *(uint2*)(drow + nt * 16 + lg * 4) = o[nt];
    }

    // layer-0 U production
    {
        short8 bf[4];
#pragma unroll
        for (int kb = 0; kb < 4; ++kb)
            bf[kb] = xchg_frag(o[2 * kb], o[2 * kb + 1]);

        floatx4 au[8];
#pragma unroll
        for (int nt = 0; nt < 8; ++nt) {
            const float4 bv = *(const float4*)&b0n[nt * 16 + lg * 4];
            au[nt] = (floatx4){bv.x, bv.y, bv.z, bv.w};
        }
#pragma unroll 2
        for (int kb = 0; kb < 4; ++kb) {
#pragma unroll
            for (int nt = 0; nt < 8; ++nt) {
                const short8 wr = *(const short8*)(Wp0n + ((size_t)(nt * 12 + 4 + kb) * 64 + lane) * 8);
                au[nt] = __builtin_amdgcn_mfma_f32_16x16x32_bf16(wr, bf[kb], au[nt], 0, 0, 0);
            }
        }
        if (node < N) {
            unsigned short* rrow = Ur + (size_t)node * 128;
#pragma unroll
            for (int nt = 0; nt < 8; ++nt) {
                uint2 u;
                u.x = f2bf_pk(au[nt][0], au[nt][1]);
                u.y = f2bf_pk(au[nt][2], au[nt][3]);
                *(uint2*)(rrow + nt * 16 + lg * 4) = u;
            }
        }
#pragma unroll
        for (int nt = 0; nt < 8; ++nt)
            au[nt] = (floatx4){0.f, 0.f, 0.f, 0.f};
#pragma unroll 2
        for (int kb = 0; kb < 4; ++kb) {
#pragma unroll
            for (int nt = 0; nt < 8; ++nt) {
                const short8 wc = *(const short8*)(Wp0n + ((size_t)(nt * 12 + 8 + kb) * 64 + lane) * 8);
                au[nt] = __builtin_amdgcn_mfma_f32_16x16x32_bf16(wc, bf[kb], au[nt], 0, 0, 0);
            }
        }
        if (node < N) {
            unsigned short* crow = Uc + (size_t)node * 128;
#pragma unroll
            for (int nt = 0; nt < 8; ++nt) {
                uint2 u;
                u.x = f2bf_pk(au[nt][0], au[nt][1]);
                u.y = f2bf_pk(au[nt][2], au[nt][3]);
                *(uint2*)(crow + nt * 16 + lg * 4) = u;
            }
        }
    }
}

// ---------------------------------------------------------------------------
// MFMA edge embedding: basis [64,32] bf16 in LDS, one K=32 MFMA pass.
// ---------------------------------------------------------------------------
__global__ __launch_bounds__(256, 4) void edge_embed_mfma_kernel(
    const float* __restrict__ pos, const int* __restrict__ row, const int* __restrict__ col,
    const unsigned short* __restrict__ Wpe, const float* __restrict__ bemb,
    unsigned short* __restrict__ h_edge)
{
    __shared__ __align__(16) unsigned short Bas[64][40];
    const int tid  = threadIdx.x;
    const int lane = tid & 63;
    const int wv   = tid >> 6;
    const int e0   = blockIdx.x * 64;

    {
        const int t = tid >> 2, q = tid & 3;
        const int rr = row[e0 + t], cc = col[e0 + t];
        const float dx = pos[rr * 3 + 0] - pos[cc * 3 + 0];
        const float dy = pos[rr * 3 + 1] - pos[cc * 3 + 1];
        const float dz = pos[rr * 3 + 2] - pos[cc * 3 + 2];
        const float d = sqrtf(dx * dx + dy * dy + dz * dz);
        const float invs = 32.0f / 5.0f;
        float e[8];
#pragma unroll
        for (int j = 0; j < 8; ++j) {
            const float mu = (float)(q * 8 + j) * (5.0f / 31.0f);
            const float tt = (d - mu) * invs;
            e[j] = __expf(-0.5f * tt * tt);
        }
        uint4 pk;
        pk.x = f2bf_pk(e[0], e[1]);
        pk.y = f2bf_pk(e[2], e[3]);
        pk.z = f2bf_pk(e[4], e[5]);
        pk.w = f2bf_pk(e[6], e[7]);
        *(uint4*)&Bas[t][q * 8] = pk;
    }
    wave_lds_fence();

    const int lr = lane & 15, lg = lane >> 4;
    floatx4 acc[8];
#pragma unroll
    for (int nt = 0; nt < 8; ++nt) {
        const float4 bv = *(const float4*)&bemb[nt * 16 + lg * 4];
        acc[nt] = (floatx4){bv.x, bv.y, bv.z, bv.w};
    }
    const short8 mf = *(const short8*)&Bas[wv * 16 + lr][lg * 8];
#pragma unroll
    for (int nt = 0; nt < 8; ++nt) {
        const short8 wf = *(const short8*)(Wpe + ((size_t)nt * 64 + lane) * 8);
        acc[nt] = __builtin_amdgcn_mfma_f32_16x16x32_bf16(wf, mf, acc[nt], 0, 0, 0);
    }
    unsigned short* erow = &h_edge[(size_t)(e0 + wv * 16 + lr) * 128];
#pragma unroll
    for (int nt = 0; nt < 8; ++nt) {
        uint2 o;
        o.x = f2bf_pk(acc[nt][0], acc[nt][1]);
        o.y = f2bf_pk(acc[nt][2], acc[nt][3]);
        *(uint2*)(erow + nt * 16 + lg * 4) = o;
    }
}

// ---------------------------------------------------------------------------
// Graph pooling (bf16 node state) + output head.
// ---------------------------------------------------------------------------
__global__ __launch_bounds__(128) void pool_kernel(
    const unsigned short* __restrict__ h_node_bf, const int* __restrict__ batch,
    float* __restrict__ sums, float* __restrict__ cnt, int N)
{
    __shared__ int bb[256];
    const int tid = threadIdx.x;
    const int n0 = blockIdx.x * 256;
    for (int idx = tid; idx < 256; idx += 128) {
        int n = n0 + idx;
        bb[idx] = (n < N) ? batch[n] : -1;
    }
    __syncthreads();
    int cur = bb[0];
    float run = 0.f, runc = 0.f;
    for (int i = 0; i < 256; ++i) {
        const int b = bb[i];
        if (b < 0) break;
        if (b != cur) {
            atomicAdd(&sums[(size_t)cur * 128 + tid], run);
            if (tid == 0) atomicAdd(&cnt[cur], runc);
            run = 0.f; runc = 0.f; cur = b;
        }
        run += bf2f(h_node_bf[(size_t)(n0 + i) * 128 + tid]);
        runc += 1.f;
    }
    atomicAdd(&sums[(size_t)cur * 128 + tid], run);
    if (tid == 0) atomicAdd(&cnt[cur], runc);
}

__global__ __launch_bounds__(256) void final_kernel(
    const float* __restrict__ sums, const float* __restrict__ cnt,
    const float* __restrict__ out_w, const float* __restrict__ out_b,
    float* __restrict__ out)
{
    const int g = threadIdx.x;
    const float c = fmaxf(cnt[g], 1.0f);
    float acc = 0.f;
    for (int jj = 0; jj < 128; ++jj) acc = fmaf(sums[(size_t)g * 128 + jj], out_w[jj], acc);
    out[g] = acc / c + out_b[0];
}

__global__ void zero_out_kernel(float* out, int n) {
    int i = blockIdx.x * 256 + threadIdx.x;
    if (i < n) out[i] = 0.f;
}

// ---------------------------------------------------------------------------

extern "C" void kernel_launch(void* const* d_in, const int* in_sizes, int n_in,
                              void* d_out, int out_size, void* d_ws, size_t ws_size,
                              hipStream_t stream)
{
    const int*   z          = (const int*)  d_in[0];
    const float* pos        = (const float*)d_in[1];
    const int*   batch      = (const int*)  d_in[2];
    const int*   eidx       = (const int*)  d_in[3];
    const float* atom_table = (const float*)d_in[4];
    const float* atom_w     = (const float*)d_in[5];
    const float* atom_b     = (const float*)d_in[6];
    const float* edge_emb_w = (const float*)d_in[7];
    const float* edge_emb_b = (const float*)d_in[8];
    const float* edge_w0    = (const float*)d_in[9];
    const float* edge_b0    = (const float*)d_in[10];
    const float* edge_w     = (const float*)d_in[11];
    const float* edge_b     = (const float*)d_in[12];
    const float* node_w     = (const float*)d_in[13];
    const float* node_b     = (const float*)d_in[14];
    const float* out_w      = (const float*)d_in[15];
    const float* out_b      = (const float*)d_in[16];
    const int* row = eidx;
    const int* col = eidx + N_EDGES_;

    // ws layout (identical footprint — known to fit). Former fp32 agg buffer
    // hosts Ur/Uc (bf16, 2x 12.8MB).
    float* aggb = (float*)d_ws;
    float* sums = aggb + (size_t)N_NODES_ * EMB;
    float* cnt  = sums + (size_t)N_GRAPH_ * EMB;
    unsigned short* h_node_bf = (unsigned short*)(cnt + N_GRAPH_);
    unsigned short* h_edge    = h_node_bf + (size_t)N_NODES_ * EMB;
    unsigned short* Wp        = h_edge + (size_t)N_EDGES_ * EMB;
    int* hist   = (int*)(Wp + WP_TOTAL);
    int* cursor = hist + N_NODES_;
    int* row_s  = cursor + N_NODES_;
    int* col_s  = row_s + N_EDGES_;

    unsigned short* Ur = (unsigned short*)aggb;
    unsigned short* Uc = Ur + (size_t)N_NODES_ * EMB;

    const size_t need = ((size_t)(N_NODES_ * EMB + N_GRAPH_ * EMB + N_GRAPH_)) * 4
                      + ((size_t)N_NODES_ * EMB + (size_t)N_EDGES_ * EMB + (size_t)WP_TOTAL) * 2
                      + ((size_t)N_NODES_ * 2 + (size_t)N_EDGES_ * 2) * 4;

    if (ws_size < need) {
        zero_out_kernel<<<1, 256, 0, stream>>>((float*)d_out, N_GRAPH_);
        return;
    }

    const int grid_rows64 = (N_NODES_ + 63) / 64;   // 782

    (void)hipMemsetAsync(hist, 0, N_NODES_ * sizeof(int), stream);
    hist_kernel<<<(N_EDGES_ + 255) / 256, 256, 0, stream>>>(row, hist);
    scan_kernel<<<1, 256, 0, stream>>>(hist, cursor);
    scatter_kernel<<<(N_EDGES_ + 255) / 256, 256, 0, stream>>>(row, col, cursor, row_s, col_s);
    // post-scatter: cursor[n] = end offset, hist[n] = degree

    pack_w_kernel<<<256, 256, 0, stream>>>(edge_w0, edge_w, atom_w, node_w, edge_emb_w, Wp);

    // atom embedding + layer-0 U
    atom_gemm_mfma_kernel<<<grid_rows64, 256, 0, stream>>>(
        atom_table, z, Wp + WP_ATOM, atom_b, h_node_bf, N_NODES_,
        Wp, edge_b0, Ur, Uc);
    edge_embed_mfma_kernel<<<N_EDGES_ / 64, 256, 0, stream>>>(
        pos, row_s, col_s, Wp + WP_EMB, edge_emb_b, h_edge);

    for (int l = 0; l < NLAYER_; ++l) {
        edge_mlp_csr_kernel<<<N_EDGES_ / 32, 128, 0, stream>>>(
            h_edge, Ur, Uc, row_s, col_s,
            Wp + (size_t)l * 114688,
            edge_b + (size_t)l * 4 * 128);
        const bool last = (l == NLAYER_ - 1);
        node_agg_gemm_kernel<<<grid_rows64, 256, 0, stream>>>(
            h_edge, hist, cursor,
            Wp + WP_NODE0 + (size_t)l * 16384, node_b + (size_t)l * 128,
            h_node_bf, N_NODES_,
            last ? (const unsigned short*)nullptr : (Wp + (size_t)(l + 1) * 114688),
            last ? edge_b0 : (edge_b0 + (size_t)(l + 1) * 128),
            Ur, Uc);
    }

    (void)hipMemsetAsync(sums, 0, ((size_t)N_GRAPH_ * EMB + N_GRAPH_) * sizeof(float), stream);
    pool_kernel<<<(N_NODES_ + 255) / 256, 128, 0, stream>>>(h_node_bf, batch, sums, cnt, N_NODES_);
    final_kernel<<<1, 256, 0, stream>>>(sums, cnt, out_w, out_b, (float*)d_out);
}

// Round 6
// 2747.715 us; speedup vs baseline: 1.3270x; 1.0906x over previous
//
#include <hip/hip_runtime.h>

#define EMB      128
#define N_NODES_ 50000
#define N_EDGES_ 800000
#define N_GRAPH_ 256
#define NLAYER_  5

// packed-weight layout offsets (ushort elements)
#define WP_ATOM  573440
#define WP_NODE0 589824
#define WP_EMB   671744
#define WP_TOTAL 675840

typedef short short8 __attribute__((ext_vector_type(8)));
typedef float floatx4 __attribute__((ext_vector_type(4)));
typedef unsigned uintx2 __attribute__((ext_vector_type(2)));

__device__ __forceinline__ float silu_f(float x) {
    return __fdividef(x, 1.0f + __expf(-x));
}
__device__ __forceinline__ float bf2f(unsigned short h) {
    return __uint_as_float(((unsigned)h) << 16);
}
__device__ __forceinline__ unsigned short f2bf(float f) {
    unsigned u = __float_as_uint(f);
    unsigned r = 0x7FFFu + ((u >> 16) & 1u);
    return (unsigned short)((u + r) >> 16);
}

#if defined(__has_builtin)
#if __has_builtin(__builtin_amdgcn_cvt_pk_bf16_f32)
#define HAVE_PK_BF16 1
#endif
#if __has_builtin(__builtin_amdgcn_permlane16_swap) && __has_builtin(__builtin_amdgcn_permlane32_swap)
#define HAVE_PERMLANE_SWAP 1
#endif
#endif

#ifdef HAVE_PK_BF16
typedef __bf16 bf16x2 __attribute__((ext_vector_type(2)));
__device__ __forceinline__ unsigned f2bf_pk(float a, float b) {
    bf16x2 v = __builtin_amdgcn_cvt_pk_bf16_f32(a, b);
    unsigned u;
    __builtin_memcpy(&u, &v, 4);
    return u;
}
#else
__device__ __forceinline__ unsigned f2bf_pk(float a, float b) {
    return (unsigned)f2bf(a) | ((unsigned)f2bf(b) << 16);
}
#endif

// wave-local LDS ordering (validated: correctness held)
__device__ __forceinline__ void wave_lds_fence() {
    __builtin_amdgcn_fence(__ATOMIC_ACQ_REL, "wavefront");
    __builtin_amdgcn_wave_barrier();
}

// async global -> LDS, 16B per lane. LDS dest = uniform base + lane*16.
__device__ __forceinline__ void gload_lds16(const unsigned short* g, unsigned short* l) {
    __builtin_amdgcn_global_load_lds(
        (const __attribute__((address_space(1))) void*)g,
        (__attribute__((address_space(3))) void*)l,
        16, 0, 0);
}

// ---------------------------------------------------------------------------
// In-wave 16-lane-row exchanges (verified numerically exact in round 4).
// Convert MFMA C-fragment uint2 packs into next-GEMM B-fragments in-register.
// ---------------------------------------------------------------------------
__device__ __forceinline__ void swap32(unsigned &a, unsigned &b) {
#ifdef HAVE_PERMLANE_SWAP
    uintx2 r = __builtin_amdgcn_permlane32_swap(a, b, false, false);
    a = r.x; b = r.y;
#else
    const int lane = (int)(threadIdx.x & 63);
    const int idx = (lane ^ 32) << 2;
    const unsigned ta = (unsigned)__builtin_amdgcn_ds_bpermute(idx, (int)a);
    const unsigned tb = (unsigned)__builtin_amdgcn_ds_bpermute(idx, (int)b);
    const bool hi = lane >= 32;
    const unsigned na = hi ? tb : a;
    const unsigned nb = hi ? b : ta;
    a = na; b = nb;
#endif
}
__device__ __forceinline__ void swap16(unsigned &a, unsigned &b) {
#ifdef HAVE_PERMLANE_SWAP
    uintx2 r = __builtin_amdgcn_permlane16_swap(a, b, false, false);
    a = r.x; b = r.y;
#else
    const unsigned ta = (unsigned)__builtin_amdgcn_ds_swizzle((int)a, 0x401F); // lane^16
    const unsigned tb = (unsigned)__builtin_amdgcn_ds_swizzle((int)b, 0x401F);
    const bool odd = ((threadIdx.x >> 4) & 1) != 0;
    const unsigned na = odd ? tb : a;
    const unsigned nb = odd ? b : ta;
    a = na; b = nb;
#endif
}

// C-frag packs of n-tiles (2kb, 2kb+1) -> B-fragment short8 for k-block kb.
__device__ __forceinline__ short8 xchg_frag(uint2 pkE, uint2 pkO) {
    unsigned a0 = pkE.x, b0 = pkO.x;
    unsigned a1 = pkE.y, b1 = pkO.y;
    swap32(a0, b0); swap16(a0, b0);
    swap32(a1, b1); swap16(a1, b1);
    union { short8 s; unsigned u[4]; } r;
    r.u[0] = a0; r.u[1] = a1; r.u[2] = b0; r.u[3] = b1;
    return r.s;
}

__device__ __forceinline__ floatx4 upair_sum(uint2 a, uint2 b) {
    floatx4 r;
    r[0] = bf2f((unsigned short)(a.x & 0xFFFF)) + bf2f((unsigned short)(b.x & 0xFFFF));
    r[1] = bf2f((unsigned short)(a.x >> 16))    + bf2f((unsigned short)(b.x >> 16));
    r[2] = bf2f((unsigned short)(a.y & 0xFFFF)) + bf2f((unsigned short)(b.y & 0xFFFF));
    r[3] = bf2f((unsigned short)(a.y >> 16))    + bf2f((unsigned short)(b.y >> 16));
    return r;
}

// ---------------------------------------------------------------------------
// Edge sort by destination row: histogram -> 1-block scan -> atomic scatter.
// ---------------------------------------------------------------------------
__global__ __launch_bounds__(256) void hist_kernel(
    const int* __restrict__ row, int* __restrict__ hist)
{
    const int e = blockIdx.x * 256 + threadIdx.x;
    if (e < N_EDGES_) atomicAdd(&hist[row[e]], 1);
}

__global__ __launch_bounds__(256) void scan_kernel(
    const int* __restrict__ hist, int* __restrict__ cursor)
{
    __shared__ int ssum[256];
    const int tid = threadIdx.x;
    const int chunk = (N_NODES_ + 255) / 256;
    const int base = tid * chunk;
    int s = 0;
    for (int i = 0; i < chunk; ++i) {
        const int idx = base + i;
        if (idx < N_NODES_) s += hist[idx];
    }
    ssum[tid] = s;
    __syncthreads();
    for (int off = 1; off < 256; off <<= 1) {
        const int t2 = (tid >= off) ? ssum[tid - off] : 0;
        __syncthreads();
        ssum[tid] += t2;
        __syncthreads();
    }
    int run = ssum[tid] - s;
    for (int i = 0; i < chunk; ++i) {
        const int idx = base + i;
        if (idx < N_NODES_) { cursor[idx] = run; run += hist[idx]; }
    }
}

__global__ __launch_bounds__(256) void scatter_kernel(
    const int* __restrict__ row, const int* __restrict__ col,
    int* __restrict__ cursor, int* __restrict__ row_s, int* __restrict__ col_s)
{
    const int e = blockIdx.x * 256 + threadIdx.x;
    if (e >= N_EDGES_) return;
    const int r = row[e];
    const int p = atomicAdd(&cursor[r], 1);
    row_s[p] = r;
    col_s[p] = col[e];
}

// ---------------------------------------------------------------------------
// Weight packing: fp32 [K][128] -> bf16 A-operand (W^T) fragment order.
// ---------------------------------------------------------------------------
__global__ __launch_bounds__(256) void pack_w_kernel(
    const float* __restrict__ edge_w0, const float* __restrict__ edge_w,
    const float* __restrict__ atom_w, const float* __restrict__ node_w,
    const float* __restrict__ edge_emb_w,
    unsigned short* __restrict__ Wp)
{
    const int bid = blockIdx.x;
    int Kb, t;
    const float* src;
    unsigned short* dst;
    if (bid < 200) {
        const int l = bid / 40, r = bid % 40, s = r / 8;
        t = r % 8;
        Kb = (s == 0) ? 12 : 4;
        src = (s == 0) ? edge_w0 + (size_t)l * 384 * 128
                       : edge_w + ((size_t)l * 4 + (s - 1)) * 128 * 128;
        dst = Wp + (size_t)l * 114688 + ((s == 0) ? 0 : (49152 + (s - 1) * 16384))
            + (size_t)t * Kb * 512;
    } else if (bid < 208) {
        t = bid - 200; Kb = 4; src = atom_w;
        dst = Wp + WP_ATOM + (size_t)t * Kb * 512;
    } else if (bid < 248) {
        const int l = (bid - 208) >> 3; t = (bid - 208) & 7; Kb = 4;
        src = node_w + (size_t)l * 128 * 128;
        dst = Wp + WP_NODE0 + (size_t)l * 16384 + (size_t)t * Kb * 512;
    } else {
        t = bid - 248; Kb = 1; src = edge_emb_w;
        dst = Wp + WP_EMB + (size_t)t * 512;
    }
    const int n = Kb * 512;
    for (int p = threadIdx.x; p < n; p += 256) {
        const int j = p & 7, lane = (p >> 3) & 63, kb = p >> 9;
        const int k  = kb * 32 + ((lane >> 4) << 3) + j;
        const int nn = t * 16 + (lane & 15);
        dst[p] = f2bf(src[(size_t)k * 128 + nn]);
    }
}

// ---------------------------------------------------------------------------
// Sorted-edge MFMA edge MLP — round-17: R3 structure (best measured: 402us)
// with fragment-major interleaved U gathers:
//   UU[node] = 256 shorts; block (lg, wv) at lg*64 + wv*16 holds
//   { Ur frag 8 shorts | Uc frag 8 shorts }  (32B, 64B-sector aligned).
//   Consumer: 2 x uint4 per edge-tile (same sector) vs 4 x uint2 scattered.
// ---------------------------------------------------------------------------
__global__ __launch_bounds__(256, 5) void edge_mlp_csr_kernel(
    unsigned short* __restrict__ h_edge,
    const unsigned short* __restrict__ UU,
    const int* __restrict__ row_s, const int* __restrict__ col_s,
    const unsigned short* __restrict__ Wp, const float* __restrict__ bh)
{
    __shared__ __align__(16) unsigned short Xs[8192];   // 16 KB
    __shared__ __align__(16) unsigned short Ys[8192];   // 16 KB

    const int tid  = threadIdx.x;
    const int e0   = blockIdx.x * 64;
    const int lane = tid & 63;
    const int wv   = tid >> 6;
    const int lr   = lane & 15;
    const int lg   = lane >> 4;
    const int nt0  = 2 * wv, nt1 = nt0 + 1;

    // edge indices for this lane's 4 e-tiles
    int rid[4], cid[4];
#pragma unroll
    for (int et = 0; et < 4; ++et) {
        const int e = e0 + et * 16 + lr;
        rid[et] = row_s[e];
        cid[et] = col_s[e];
    }

    // async stage: Xs <- h_edge (chunk-swizzled source, linear LDS dest)
    const int srow = 16 * wv + lg;
#pragma unroll
    for (int j = 0; j < 4; ++j) {
        const int r = srow + 4 * j;
        const int c = lr ^ (r & 7);
        gload_lds16(h_edge + (size_t)(e0 + r) * 128 + c * 8,
                    &Xs[(16 * wv + 4 * j) * 128]);
    }

    // U gathers: one 16B Ur load + one 16B Uc load per edge-tile, same sector
    const int uoff = lg * 64 + wv * 16;
    uint4 ur4[4], uc4[4];
#pragma unroll
    for (int et = 0; et < 4; ++et) {
        ur4[et] = *(const uint4*)(UU + (size_t)rid[et] * 256 + uoff);
        uc4[et] = *(const uint4*)(UU + (size_t)cid[et] * 256 + uoff + 8);
    }

    asm volatile("s_waitcnt vmcnt(0)" ::: "memory");
    __syncthreads();

    // acc seed = Ur[row] + Uc[col]   (b0 folded into Ur)
    floatx4 acc0[4], acc1[4];
#pragma unroll
    for (int et = 0; et < 4; ++et) {
        uint2 ra, rb, ca, cb;
        ra.x = ur4[et].x; ra.y = ur4[et].y;   // nt0 fragment
        rb.x = ur4[et].z; rb.y = ur4[et].w;   // nt1 fragment
        ca.x = uc4[et].x; ca.y = uc4[et].y;
        cb.x = uc4[et].z; cb.y = uc4[et].w;
        acc0[et] = upair_sum(ra, ca);
        acc1[et] = upair_sum(rb, cb);
    }

    // ---- stage 0 : K = 128 over h_edge (kb 0..3 of the packed slab) -------
    const unsigned short* aptr0 = Wp + ((size_t)(nt0 * 12) * 64 + lane) * 8;
    const unsigned short* aptr1 = Wp + ((size_t)(nt1 * 12) * 64 + lane) * 8;
#pragma unroll 2
    for (int kk = 0; kk < 4; ++kk) {
        const short8 wf0 = *(const short8*)(aptr0 + (size_t)kk * 512);
        const short8 wf1 = *(const short8*)(aptr1 + (size_t)kk * 512);
#pragma unroll
        for (int et = 0; et < 4; ++et) {
            const int r = et * 16 + lr;
            const short8 mf = *(const short8*)&Xs[r * 128 + (((kk * 4 + lg) ^ (r & 7)) << 3)];
            acc0[et] = __builtin_amdgcn_mfma_f32_16x16x32_bf16(wf0, mf, acc0[et], 0, 0, 0);
            acc1[et] = __builtin_amdgcn_mfma_f32_16x16x32_bf16(wf1, mf, acc1[et], 0, 0, 0);
        }
    }

    // residual copy for epilogue, read from Xs while it is still intact
    const int t_ = tid >> 2, q_ = tid & 3;
    short8 he_reg[4];
#pragma unroll
    for (int i = 0; i < 4; ++i) {
        const int ch = q_ + 4 * i;
        he_reg[i] = *(const short8*)&Xs[t_ * 128 + ((ch ^ (t_ & 7)) << 3)];
    }

    // stage-0 out -> Ys
#pragma unroll
    for (int et = 0; et < 4; ++et) {
        const int r = et * 16 + lr;
        uint2 p0, p1;
        p0.x = f2bf_pk(silu_f(acc0[et][0]), silu_f(acc0[et][1]));
        p0.y = f2bf_pk(silu_f(acc0[et][2]), silu_f(acc0[et][3]));
        p1.x = f2bf_pk(silu_f(acc1[et][0]), silu_f(acc1[et][1]));
        p1.y = f2bf_pk(silu_f(acc1[et][2]), silu_f(acc1[et][3]));
        const int c0 = (2 * nt0 + (lg >> 1)) ^ (r & 7);
        const int c1 = (2 * nt1 + (lg >> 1)) ^ (r & 7);
        *(uint2*)&Ys[r * 128 + c0 * 8 + (lg & 1) * 4] = p0;
        *(uint2*)&Ys[r * 128 + c1 * 8 + (lg & 1) * 4] = p1;
    }
    __syncthreads();

    // ---- stages 1..4 : K = 128, ping-pong Y->X->Y->X->Y -------------------
#pragma unroll 1
    for (int s = 1; s < 5; ++s) {
        const unsigned short* bin = (s & 1) ? Ys : Xs;
        unsigned short* bout      = (s & 1) ? Xs : Ys;
        const unsigned short* __restrict__ Ws = Wp + 49152 + (size_t)(s - 1) * 16384;
        const float* __restrict__ bias = bh + (size_t)(s - 1) * 128;

        const float4 bv0 = *(const float4*)&bias[nt0 * 16 + lg * 4];
        const float4 bv1 = *(const float4*)&bias[nt1 * 16 + lg * 4];
#pragma unroll
        for (int et = 0; et < 4; ++et) {
            acc0[et] = (floatx4){bv0.x, bv0.y, bv0.z, bv0.w};
            acc1[et] = (floatx4){bv1.x, bv1.y, bv1.z, bv1.w};
        }
        const unsigned short* ap0 = Ws + ((size_t)(nt0 * 4) * 64 + lane) * 8;
        const unsigned short* ap1 = Ws + ((size_t)(nt1 * 4) * 64 + lane) * 8;
#pragma unroll 2
        for (int kk = 0; kk < 4; ++kk) {
            const short8 wf0 = *(const short8*)(ap0 + (size_t)kk * 512);
            const short8 wf1 = *(const short8*)(ap1 + (size_t)kk * 512);
#pragma unroll
            for (int et = 0; et < 4; ++et) {
                const int r = et * 16 + lr;
                const short8 mf = *(const short8*)&bin[r * 128 + (((kk * 4 + lg) ^ (r & 7)) << 3)];
                acc0[et] = __builtin_amdgcn_mfma_f32_16x16x32_bf16(wf0, mf, acc0[et], 0, 0, 0);
                acc1[et] = __builtin_amdgcn_mfma_f32_16x16x32_bf16(wf1, mf, acc1[et], 0, 0, 0);
            }
        }
#pragma unroll
        for (int et = 0; et < 4; ++et) {
            const int r = et * 16 + lr;
            uint2 p0, p1;
            p0.x = f2bf_pk(silu_f(acc0[et][0]), silu_f(acc0[et][1]));
            p0.y = f2bf_pk(silu_f(acc0[et][2]), silu_f(acc0[et][3]));
            p1.x = f2bf_pk(silu_f(acc1[et][0]), silu_f(acc1[et][1]));
            p1.y = f2bf_pk(silu_f(acc1[et][2]), silu_f(acc1[et][3]));
            const int c0 = (2 * nt0 + (lg >> 1)) ^ (r & 7);
            const int c1 = (2 * nt1 + (lg >> 1)) ^ (r & 7);
            *(uint2*)&bout[r * 128 + c0 * 8 + (lg & 1) * 4] = p0;
            *(uint2*)&bout[r * 128 + c1 * 8 + (lg & 1) * 4] = p1;
        }
        __syncthreads();
    }

    // ---- epilogue: h_edge = he_reg + m (stage-4 out in Y); 16B stores -----
#pragma unroll
    for (int i = 0; i < 4; ++i) {
        const int ch = q_ + 4 * i;
        const short8 mv = *(const short8*)&Ys[t_ * 128 + ((ch ^ (t_ & 7)) << 3)];
        const short8 ov = he_reg[i];
        float v[8];
#pragma unroll
        for (int j = 0; j < 8; ++j)
            v[j] = bf2f((unsigned short)ov[j]) + bf2f((unsigned short)mv[j]);
        uint4 sv;
        sv.x = f2bf_pk(v[0], v[1]);
        sv.y = f2bf_pk(v[2], v[3]);
        sv.z = f2bf_pk(v[4], v[5]);
        sv.w = f2bf_pk(v[6], v[7]);
        *(uint4*)(h_edge + (size_t)(e0 + t_) * 128 + ch * 8) = sv;
    }
}

// ---------------------------------------------------------------------------
// Fused CSR segment-sum + MFMA node update + NEXT-LAYER U production:
//   agg[n] = sum of h_edge rows in CSR run (fp32)
//   h_node[n] += silu(agg @ node_w + node_b)
//   if (Wp0n): UU[n] = { h_new @ W0r + b0n | h_new @ W0c }  fragment-major.
// ---------------------------------------------------------------------------
__global__ __launch_bounds__(256, 3) void node_agg_gemm_kernel(
    const unsigned short* __restrict__ h_edge,
    const int* __restrict__ hist, const int* __restrict__ cur_end,
    const unsigned short* __restrict__ Wpm, const float* __restrict__ bias,
    unsigned short* __restrict__ h_node_bf, int N,
    const unsigned short* __restrict__ Wp0n, const float* __restrict__ b0n,
    unsigned short* __restrict__ UU)
{
    __shared__ __align__(16) unsigned short B[64][136];
    const int tid  = threadIdx.x;
    const int lane = tid & 63;
    const int wv   = tid >> 6;
    const int n0   = blockIdx.x * 64;

    {
        const int t = tid >> 2, q = tid & 3;
        const int n = n0 + t;
        float a[32];
#pragma unroll
        for (int j = 0; j < 32; ++j) a[j] = 0.f;
        if (n < N) {
            const int e_end = cur_end[n];
            const int e_beg = e_end - hist[n];
            for (int e = e_beg; e < e_end; ++e) {
                const unsigned short* p = &h_edge[(size_t)e * 128 + q * 32];
#pragma unroll
                for (int g = 0; g < 4; ++g) {
                    const short8 v = *(const short8*)(p + g * 8);
#pragma unroll
                    for (int j = 0; j < 8; ++j)
                        a[g * 8 + j] += bf2f((unsigned short)v[j]);
                }
            }
        }
#pragma unroll
        for (int g = 0; g < 4; ++g) {
            uint4 pk;
            pk.x = f2bf_pk(a[g * 8 + 0], a[g * 8 + 1]);
            pk.y = f2bf_pk(a[g * 8 + 2], a[g * 8 + 3]);
            pk.z = f2bf_pk(a[g * 8 + 4], a[g * 8 + 5]);
            pk.w = f2bf_pk(a[g * 8 + 6], a[g * 8 + 7]);
            *(uint4*)&B[t][q * 32 + g * 8] = pk;
        }
    }
    wave_lds_fence();

    const int lr = lane & 15, lg = lane >> 4;
    floatx4 acc[8];
#pragma unroll
    for (int nt = 0; nt < 8; ++nt) {
        const float4 bv = *(const float4*)&bias[nt * 16 + lg * 4];
        acc[nt] = (floatx4){bv.x, bv.y, bv.z, bv.w};
    }
    const unsigned short* brow = &B[wv * 16 + lr][0];
#pragma unroll 2
    for (int kb = 0; kb < 4; ++kb) {
        const short8 mf = *(const short8*)(brow + kb * 32 + lg * 8);
#pragma unroll
        for (int nt = 0; nt < 8; ++nt) {
            const short8 wf = *(const short8*)(Wpm + ((size_t)(nt * 4 + kb) * 64 + lane) * 8);
            acc[nt] = __builtin_amdgcn_mfma_f32_16x16x32_bf16(wf, mf, acc[nt], 0, 0, 0);
        }
    }
    const int node = n0 + wv * 16 + lr;
    unsigned short* drow = &h_node_bf[(size_t)node * 128];

    uint2 o[8];
#pragma unroll
    for (int nt = 0; nt < 8; ++nt) {
        float x0 = silu_f(acc[nt][0]), x1 = silu_f(acc[nt][1]);
        float x2 = silu_f(acc[nt][2]), x3 = silu_f(acc[nt][3]);
        if (node < N) {
            const uint2 d = *(const uint2*)(drow + nt * 16 + lg * 4);
            x0 += bf2f((unsigned short)(d.x & 0xFFFF));
            x1 += bf2f((unsigned short)(d.x >> 16));
            x2 += bf2f((unsigned short)(d.y & 0xFFFF));
            x3 += bf2f((unsigned short)(d.y >> 16));
        }
        o[nt].x = f2bf_pk(x0, x1);
        o[nt].y = f2bf_pk(x2, x3);
    }
    if (node < N) {
#pragma unroll
        for (int nt = 0; nt < 8; ++nt)
            *(uint2*)(drow + nt * 16 + lg * 4) = o[nt];
    }

    if (Wp0n) {
        short8 bf[4];
#pragma unroll
        for (int kb = 0; kb < 4; ++kb)
            bf[kb] = xchg_frag(o[2 * kb], o[2 * kb + 1]);

        // Ur = h_new @ W0r + b0n
        floatx4 au[8];
#pragma unroll
        for (int nt = 0; nt < 8; ++nt) {
            const float4 bv = *(const float4*)&b0n[nt * 16 + lg * 4];
            au[nt] = (floatx4){bv.x, bv.y, bv.z, bv.w};
        }
#pragma unroll 2
        for (int kb = 0; kb < 4; ++kb) {
#pragma unroll
            for (int nt = 0; nt < 8; ++nt) {
                const short8 wr = *(const short8*)(Wp0n + ((size_t)(nt * 12 + 4 + kb) * 64 + lane) * 8);
                au[nt] = __builtin_amdgcn_mfma_f32_16x16x32_bf16(wr, bf[kb], au[nt], 0, 0, 0);
            }
        }
        if (node < N) {
            unsigned short* urow = UU + (size_t)node * 256;
            // fragment-major interleaved: Ur frag for (nt) at lg*64 + (nt>>1)*16 + (nt&1)*4
#pragma unroll
            for (int nt = 0; nt < 8; ++nt) {
                uint2 u;
                u.x = f2bf_pk(au[nt][0], au[nt][1]);
                u.y = f2bf_pk(au[nt][2], au[nt][3]);
                *(uint2*)(urow + lg * 64 + (nt >> 1) * 16 + (nt & 1) * 4) = u;
            }
        }
        // Uc = h_new @ W0c
#pragma unroll
        for (int nt = 0; nt < 8; ++nt)
            au[nt] = (floatx4){0.f, 0.f, 0.f, 0.f};
#pragma unroll 2
        for (int kb = 0; kb < 4; ++kb) {
#pragma unroll
            for (int nt = 0; nt < 8; ++nt) {
                const short8 wc = *(const short8*)(Wp0n + ((size_t)(nt * 12 + 8 + kb) * 64 + lane) * 8);
                au[nt] = __builtin_amdgcn_mfma_f32_16x16x32_bf16(wc, bf[kb], au[nt], 0, 0, 0);
            }
        }
        if (node < N) {
            unsigned short* urow = UU + (size_t)node * 256;
#pragma unroll
            for (int nt = 0; nt < 8; ++nt) {
                uint2 u;
                u.x = f2bf_pk(au[nt][0], au[nt][1]);
                u.y = f2bf_pk(au[nt][2], au[nt][3]);
                *(uint2*)(urow + lg * 64 + (nt >> 1) * 16 + (nt & 1) * 4 + 8) = u;
            }
        }
    }
}

// ---------------------------------------------------------------------------
// MFMA row GEMM (atom embedding) + layer-0 U production (same fusion).
// ---------------------------------------------------------------------------
__global__ __launch_bounds__(256, 3) void atom_gemm_mfma_kernel(
    const float* __restrict__ src, const int* __restrict__ gidx,
    const unsigned short* __restrict__ Wpm, const float* __restrict__ bias,
    unsigned short* __restrict__ dst, int N,
    const unsigned short* __restrict__ Wp0n, const float* __restrict__ b0n,
    unsigned short* __restrict__ UU)
{
    __shared__ __align__(16) unsigned short B[64][136];
    const int tid  = threadIdx.x;
    const int lane = tid & 63;
    const int wv   = tid >> 6;
    const int n0   = blockIdx.x * 64;

    {
        const int t = tid >> 2, q = tid & 3;
        const int node = n0 + t;
        const float* srow = src;
        if (node < N) srow = &src[(size_t)gidx[node] * 128];
#pragma unroll
        for (int i = 0; i < 4; ++i) {
            const int k8 = (q + 4 * i) << 3;
            uint4 pk = make_uint4(0, 0, 0, 0);
            if (node < N) {
                const float4 f0 = *(const float4*)(srow + k8);
                const float4 f1 = *(const float4*)(srow + k8 + 4);
                pk.x = f2bf_pk(f0.x, f0.y);
                pk.y = f2bf_pk(f0.z, f0.w);
                pk.z = f2bf_pk(f1.x, f1.y);
                pk.w = f2bf_pk(f1.z, f1.w);
            }
            *(uint4*)&B[t][k8] = pk;
        }
    }
    wave_lds_fence();

    const int lr = lane & 15, lg = lane >> 4;
    floatx4 acc[8];
#pragma unroll
    for (int nt = 0; nt < 8; ++nt) {
        const float4 bv = *(const float4*)&bias[nt * 16 + lg * 4];
        acc[nt] = (floatx4){bv.x, bv.y, bv.z, bv.w};
    }
    const unsigned short* brow = &B[wv * 16 + lr][0];
#pragma unroll 2
    for (int kb = 0; kb < 4; ++kb) {
        const short8 mf = *(const short8*)(brow + kb * 32 + lg * 8);
#pragma unroll
        for (int nt = 0; nt < 8; ++nt) {
            const short8 wf = *(const short8*)(Wpm + ((size_t)(nt * 4 + kb) * 64 + lane) * 8);
            acc[nt] = __builtin_amdgcn_mfma_f32_16x16x32_bf16(wf, mf, acc[nt], 0, 0, 0);
        }
    }
    const int node = n0 + wv * 16 + lr;
    uint2 o[8];
#pragma unroll
    for (int nt = 0; nt < 8; ++nt) {
        o[nt].x = f2bf_pk(acc[nt][0], acc[nt][1]);
        o[nt].y = f2bf_pk(acc[nt][2], acc[nt][3]);
    }
    if (node < N) {
        unsigned short* drow = &dst[(size_t)node * 128];
#pragma unroll
        for (int nt = 0; nt < 8; ++nt)
            *(uint2*)(drow + nt * 16 + lg * 4) = o[nt];
    }

    // layer-0 U production (fragment-major interleaved UU)
    {
        short8 bf[4];
#pragma unroll
        for (int kb = 0; kb < 4; ++kb)
            bf[kb] = xchg_frag(o[2 * kb], o[2 * kb + 1]);

        floatx4 au[8];
#pragma unroll
        for (int nt = 0; nt < 8; ++nt) {
            const float4 bv = *(const float4*)&b0n[nt * 16 + lg * 4];
            au[nt] = (floatx4){bv.x, bv.y, bv.z, bv.w};
        }
#pragma unroll 2
        for (int kb = 0; kb < 4; ++kb) {
#pragma unroll
            for (int nt = 0; nt < 8; ++nt) {
                const short8 wr = *(const short8*)(Wp0n + ((size_t)(nt * 12 + 4 + kb) * 64 + lane) * 8);
                au[nt] = __builtin_amdgcn_mfma_f32_16x16x32_bf16(wr, bf[kb], au[nt], 0, 0, 0);
            }
        }
        if (node < N) {
            unsigned short* urow = UU + (size_t)node * 256;
#pragma unroll
            for (int nt = 0; nt < 8; ++nt) {
                uint2 u;
                u.x = f2bf_pk(au[nt][0], au[nt][1]);
                u.y = f2bf_pk(au[nt][2], au[nt][3]);
                *(uint2*)(urow + lg * 64 + (nt >> 1) * 16 + (nt & 1) * 4) = u;
            }
        }
#pragma unroll
        for (int nt = 0; nt < 8; ++nt)
            au[nt] = (floatx4){0.f, 0.f, 0.f, 0.f};
#pragma unroll 2
        for (int kb = 0; kb < 4; ++kb) {
#pragma unroll
            for (int nt = 0; nt < 8; ++nt) {
                const short8 wc = *(const short8*)(Wp0n + ((size_t)(nt * 12 + 8 + kb) * 64 + lane) * 8);
                au[nt] = __builtin_amdgcn_mfma_f32_16x16x32_bf16(wc, bf[kb], au[nt], 0, 0, 0);
            }
        }
        if (node < N) {
            unsigned short* urow = UU + (size_t)node * 256;
#pragma unroll
            for (int nt = 0; nt < 8; ++nt) {
                uint2 u;
                u.x = f2bf_pk(au[nt][0], au[nt][1]);
                u.y = f2bf_pk(au[nt][2], au[nt][3]);
                *(uint2*)(urow + lg * 64 + (nt >> 1) * 16 + (nt & 1) * 4 + 8) = u;
            }
        }
    }
}

// ---------------------------------------------------------------------------
// MFMA edge embedding: basis [64,32] bf16 in LDS, one K=32 MFMA pass.
// ---------------------------------------------------------------------------
__global__ __launch_bounds__(256, 4) void edge_embed_mfma_kernel(
    const float* __restrict__ pos, const int* __restrict__ row, const int* __restrict__ col,
    const unsigned short* __restrict__ Wpe, const float* __restrict__ bemb,
    unsigned short* __restrict__ h_edge)
{
    __shared__ __align__(16) unsigned short Bas[64][40];
    const int tid  = threadIdx.x;
    const int lane = tid & 63;
    const int wv   = tid >> 6;
    const int e0   = blockIdx.x * 64;

    {
        const int t = tid >> 2, q = tid & 3;
        const int rr = row[e0 + t], cc = col[e0 + t];
        const float dx = pos[rr * 3 + 0] - pos[cc * 3 + 0];
        const float dy = pos[rr * 3 + 1] - pos[cc * 3 + 1];
        const float dz = pos[rr * 3 + 2] - pos[cc * 3 + 2];
        const float d = sqrtf(dx * dx + dy * dy + dz * dz);
        const float invs = 32.0f / 5.0f;
        float e[8];
#pragma unroll
        for (int j = 0; j < 8; ++j) {
            const float mu = (float)(q * 8 + j) * (5.0f / 31.0f);
            const float tt = (d - mu) * invs;
            e[j] = __expf(-0.5f * tt * tt);
        }
        uint4 pk;
        pk.x = f2bf_pk(e[0], e[1]);
        pk.y = f2bf_pk(e[2], e[3]);
        pk.z = f2bf_pk(e[4], e[5]);
        pk.w = f2bf_pk(e[6], e[7]);
        *(uint4*)&Bas[t][q * 8] = pk;
    }
    wave_lds_fence();

    const int lr = lane & 15, lg = lane >> 4;
    floatx4 acc[8];
#pragma unroll
    for (int nt = 0; nt < 8; ++nt) {
        const float4 bv = *(const float4*)&bemb[nt * 16 + lg * 4];
        acc[nt] = (floatx4){bv.x, bv.y, bv.z, bv.w};
    }
    const short8 mf = *(const short8*)&Bas[wv * 16 + lr][lg * 8];
#pragma unroll
    for (int nt = 0; nt < 8; ++nt) {
        const short8 wf = *(const short8*)(Wpe + ((size_t)nt * 64 + lane) * 8);
        acc[nt] = __builtin_amdgcn_mfma_f32_16x16x32_bf16(wf, mf, acc[nt], 0, 0, 0);
    }
    unsigned short* erow = &h_edge[(size_t)(e0 + wv * 16 + lr) * 128];
#pragma unroll
    for (int nt = 0; nt < 8; ++nt) {
        uint2 o;
        o.x = f2bf_pk(acc[nt][0], acc[nt][1]);
        o.y = f2bf_pk(acc[nt][2], acc[nt][3]);
        *(uint2*)(erow + nt * 16 + lg * 4) = o;
    }
}

// ---------------------------------------------------------------------------
// Graph pooling (bf16 node state) + output head.
// ---------------------------------------------------------------------------
__global__ __launch_bounds__(128) void pool_kernel(
    const unsigned short* __restrict__ h_node_bf, const int* __restrict__ batch,
    float* __restrict__ sums, float* __restrict__ cnt, int N)
{
    __shared__ int bb[256];
    const int tid = threadIdx.x;
    const int n0 = blockIdx.x * 256;
    for (int idx = tid; idx < 256; idx += 128) {
        int n = n0 + idx;
        bb[idx] = (n < N) ? batch[n] : -1;
    }
    __syncthreads();
    int cur = bb[0];
    float run = 0.f, runc = 0.f;
    for (int i = 0; i < 256; ++i) {
        const int b = bb[i];
        if (b < 0) break;
        if (b != cur) {
            atomicAdd(&sums[(size_t)cur * 128 + tid], run);
            if (tid == 0) atomicAdd(&cnt[cur], runc);
            run = 0.f; runc = 0.f; cur = b;
        }
        run += bf2f(h_node_bf[(size_t)(n0 + i) * 128 + tid]);
        runc += 1.f;
    }
    atomicAdd(&sums[(size_t)cur * 128 + tid], run);
    if (tid == 0) atomicAdd(&cnt[cur], runc);
}

__global__ __launch_bounds__(256) void final_kernel(
    const float* __restrict__ sums, const float* __restrict__ cnt,
    const float* __restrict__ out_w, const float* __restrict__ out_b,
    float* __restrict__ out)
{
    const int g = threadIdx.x;
    const float c = fmaxf(cnt[g], 1.0f);
    float acc = 0.f;
    for (int jj = 0; jj < 128; ++jj) acc = fmaf(sums[(size_t)g * 128 + jj], out_w[jj], acc);
    out[g] = acc / c + out_b[0];
}

__global__ void zero_out_kernel(float* out, int n) {
    int i = blockIdx.x * 256 + threadIdx.x;
    if (i < n) out[i] = 0.f;
}

// ---------------------------------------------------------------------------

extern "C" void kernel_launch(void* const* d_in, const int* in_sizes, int n_in,
                              void* d_out, int out_size, void* d_ws, size_t ws_size,
                              hipStream_t stream)
{
    const int*   z          = (const int*)  d_in[0];
    const float* pos        = (const float*)d_in[1];
    const int*   batch      = (const int*)  d_in[2];
    const int*   eidx       = (const int*)  d_in[3];
    const float* atom_table = (const float*)d_in[4];
    const float* atom_w     = (const float*)d_in[5];
    const float* atom_b     = (const float*)d_in[6];
    const float* edge_emb_w = (const float*)d_in[7];
    const float* edge_emb_b = (const float*)d_in[8];
    const float* edge_w0    = (const float*)d_in[9];
    const float* edge_b0    = (const float*)d_in[10];
    const float* edge_w     = (const float*)d_in[11];
    const float* edge_b     = (const float*)d_in[12];
    const float* node_w     = (const float*)d_in[13];
    const float* node_b     = (const float*)d_in[14];
    const float* out_w      = (const float*)d_in[15];
    const float* out_b      = (const float*)d_in[16];
    const int* row = eidx;
    const int* col = eidx + N_EDGES_;

    // ws layout (identical footprint — known to fit). Former fp32 agg buffer
    // hosts UU (interleaved Ur|Uc, bf16, 25.6MB).
    float* aggb = (float*)d_ws;
    float* sums = aggb + (size_t)N_NODES_ * EMB;
    float* cnt  = sums + (size_t)N_GRAPH_ * EMB;
    unsigned short* h_node_bf = (unsigned short*)(cnt + N_GRAPH_);
    unsigned short* h_edge    = h_node_bf + (size_t)N_NODES_ * EMB;
    unsigned short* Wp        = h_edge + (size_t)N_EDGES_ * EMB;
    int* hist   = (int*)(Wp + WP_TOTAL);
    int* cursor = hist + N_NODES_;
    int* row_s  = cursor + N_NODES_;
    int* col_s  = row_s + N_EDGES_;

    unsigned short* UU = (unsigned short*)aggb;   // [node][256] shorts

    const size_t need = ((size_t)(N_NODES_ * EMB + N_GRAPH_ * EMB + N_GRAPH_)) * 4
                      + ((size_t)N_NODES_ * EMB + (size_t)N_EDGES_ * EMB + (size_t)WP_TOTAL) * 2
                      + ((size_t)N_NODES_ * 2 + (size_t)N_EDGES_ * 2) * 4;

    if (ws_size < need) {
        zero_out_kernel<<<1, 256, 0, stream>>>((float*)d_out, N_GRAPH_);
        return;
    }

    const int grid_rows64 = (N_NODES_ + 63) / 64;   // 782

    (void)hipMemsetAsync(hist, 0, N_NODES_ * sizeof(int), stream);
    hist_kernel<<<(N_EDGES_ + 255) / 256, 256, 0, stream>>>(row, hist);
    scan_kernel<<<1, 256, 0, stream>>>(hist, cursor);
    scatter_kernel<<<(N_EDGES_ + 255) / 256, 256, 0, stream>>>(row, col, cursor, row_s, col_s);
    // post-scatter: cursor[n] = end offset, hist[n] = degree

    pack_w_kernel<<<256, 256, 0, stream>>>(edge_w0, edge_w, atom_w, node_w, edge_emb_w, Wp);

    // atom embedding + layer-0 U
    atom_gemm_mfma_kernel<<<grid_rows64, 256, 0, stream>>>(
        atom_table, z, Wp + WP_ATOM, atom_b, h_node_bf, N_NODES_,
        Wp, edge_b0, UU);
    edge_embed_mfma_kernel<<<N_EDGES_ / 64, 256, 0, stream>>>(
        pos, row_s, col_s, Wp + WP_EMB, edge_emb_b, h_edge);

    for (int l = 0; l < NLAYER_; ++l) {
        edge_mlp_csr_kernel<<<N_EDGES_ / 64, 256, 0, stream>>>(
            h_edge, UU, row_s, col_s,
            Wp + (size_t)l * 114688,
            edge_b + (size_t)l * 4 * 128);
        const bool last = (l == NLAYER_ - 1);
        node_agg_gemm_kernel<<<grid_rows64, 256, 0, stream>>>(
            h_edge, hist, cursor,
            Wp + WP_NODE0 + (size_t)l * 16384, node_b + (size_t)l * 128,
            h_node_bf, N_NODES_,
            last ? (const unsigned short*)nullptr : (Wp + (size_t)(l + 1) * 114688),
            last ? edge_b0 : (edge_b0 + (size_t)(l + 1) * 128),
            UU);
    }

    (void)hipMemsetAsync(sums, 0, ((size_t)N_GRAPH_ * EMB + N_GRAPH_) * sizeof(float), stream);
    pool_kernel<<<(N_NODES_ + 255) / 256, 128, 0, stream>>>(h_node_bf, batch, sums, cnt, N_NODES_);
    final_kernel<<<1, 256, 0, stream>>>(sums, cnt, out_w, out_b, (float*)d_out);
}

// Round 7
// 2594.872 us; speedup vs baseline: 1.4052x; 1.0589x over previous
//
#include <hip/hip_runtime.h>

#define EMB      128
#define N_NODES_ 50000
#define N_EDGES_ 800000
#define N_GRAPH_ 256
#define NLAYER_  5

// edge tile: 48 edges/block, 16-row pad at end of h_edge for the tail block
#define ETILE_   48
#define EPAD_    16

// packed-weight layout offsets (ushort elements)
#define WP_ATOM  573440
#define WP_NODE0 589824
#define WP_EMB   671744
#define WP_TOTAL 675840

typedef short short8 __attribute__((ext_vector_type(8)));
typedef float floatx4 __attribute__((ext_vector_type(4)));

__device__ __forceinline__ float silu_f(float x) {
    return __fdividef(x, 1.0f + __expf(-x));
}
__device__ __forceinline__ float bf2f(unsigned short h) {
    return __uint_as_float(((unsigned)h) << 16);
}
__device__ __forceinline__ unsigned short f2bf(float f) {
    unsigned u = __float_as_uint(f);
    unsigned r = 0x7FFFu + ((u >> 16) & 1u);
    return (unsigned short)((u + r) >> 16);
}

#if defined(__has_builtin)
#if __has_builtin(__builtin_amdgcn_cvt_pk_bf16_f32)
#define HAVE_PK_BF16 1
#endif
#endif
#ifdef HAVE_PK_BF16
typedef __bf16 bf16x2 __attribute__((ext_vector_type(2)));
__device__ __forceinline__ unsigned f2bf_pk(float a, float b) {
    bf16x2 v = __builtin_amdgcn_cvt_pk_bf16_f32(a, b);
    unsigned u;
    __builtin_memcpy(&u, &v, 4);
    return u;
}
#else
__device__ __forceinline__ unsigned f2bf_pk(float a, float b) {
    return (unsigned)f2bf(a) | ((unsigned)f2bf(b) << 16);
}
#endif

// wave-local LDS ordering (validated round 9: correctness held)
__device__ __forceinline__ void wave_lds_fence() {
    __builtin_amdgcn_fence(__ATOMIC_ACQ_REL, "wavefront");
    __builtin_amdgcn_wave_barrier();
}

// async global -> LDS, 16B per lane. LDS dest = uniform base + lane*16.
__device__ __forceinline__ void gload_lds16(const unsigned short* g, unsigned short* l) {
    __builtin_amdgcn_global_load_lds(
        (const __attribute__((address_space(1))) void*)g,
        (__attribute__((address_space(3))) void*)l,
        16, 0, 0);
}

// ---------------------------------------------------------------------------
// Edge sort by destination row: histogram -> 1-block scan -> atomic scatter.
// After scatter: cursor[n] = END offset of node n's edge run; hist[n] = degree.
// ---------------------------------------------------------------------------
__global__ __launch_bounds__(256) void hist_kernel(
    const int* __restrict__ row, int* __restrict__ hist)
{
    const int e = blockIdx.x * 256 + threadIdx.x;
    if (e < N_EDGES_) atomicAdd(&hist[row[e]], 1);
}

__global__ __launch_bounds__(256) void scan_kernel(
    const int* __restrict__ hist, int* __restrict__ cursor)
{
    __shared__ int ssum[256];
    const int tid = threadIdx.x;
    const int chunk = (N_NODES_ + 255) / 256;
    const int base = tid * chunk;
    int s = 0;
    for (int i = 0; i < chunk; ++i) {
        const int idx = base + i;
        if (idx < N_NODES_) s += hist[idx];
    }
    ssum[tid] = s;
    __syncthreads();
    for (int off = 1; off < 256; off <<= 1) {
        const int t2 = (tid >= off) ? ssum[tid - off] : 0;
        __syncthreads();
        ssum[tid] += t2;
        __syncthreads();
    }
    int run = ssum[tid] - s;
    for (int i = 0; i < chunk; ++i) {
        const int idx = base + i;
        if (idx < N_NODES_) { cursor[idx] = run; run += hist[idx]; }
    }
}

__global__ __launch_bounds__(256) void scatter_kernel(
    const int* __restrict__ row, const int* __restrict__ col,
    int* __restrict__ cursor, int* __restrict__ row_s, int* __restrict__ col_s)
{
    const int e = blockIdx.x * 256 + threadIdx.x;
    if (e >= N_EDGES_) return;
    const int r = row[e];
    const int p = atomicAdd(&cursor[r], 1);
    row_s[p] = r;
    col_s[p] = col[e];
}

// ---------------------------------------------------------------------------
// Weight packing: fp32 [K][128] -> bf16 A-operand (W^T) fragment order.
// 256 blocks: 0..199 edge MLP | 200..207 atom_w | 208..247 node_w | 248..255 emb
// ---------------------------------------------------------------------------
__global__ __launch_bounds__(256) void pack_w_kernel(
    const float* __restrict__ edge_w0, const float* __restrict__ edge_w,
    const float* __restrict__ atom_w, const float* __restrict__ node_w,
    const float* __restrict__ edge_emb_w,
    unsigned short* __restrict__ Wp)
{
    const int bid = blockIdx.x;
    int Kb, t;
    const float* src;
    unsigned short* dst;
    if (bid < 200) {
        const int l = bid / 40, r = bid % 40, s = r / 8;
        t = r % 8;
        Kb = (s == 0) ? 12 : 4;
        src = (s == 0) ? edge_w0 + (size_t)l * 384 * 128
                       : edge_w + ((size_t)l * 4 + (s - 1)) * 128 * 128;
        dst = Wp + (size_t)l * 114688 + ((s == 0) ? 0 : (49152 + (s - 1) * 16384))
            + (size_t)t * Kb * 512;
    } else if (bid < 208) {
        t = bid - 200; Kb = 4; src = atom_w;
        dst = Wp + WP_ATOM + (size_t)t * Kb * 512;
    } else if (bid < 248) {
        const int l = (bid - 208) >> 3; t = (bid - 208) & 7; Kb = 4;
        src = node_w + (size_t)l * 128 * 128;
        dst = Wp + WP_NODE0 + (size_t)l * 16384 + (size_t)t * Kb * 512;
    } else {
        t = bid - 248; Kb = 1; src = edge_emb_w;
        dst = Wp + WP_EMB + (size_t)t * 512;
    }
    const int n = Kb * 512;
    for (int p = threadIdx.x; p < n; p += 256) {
        const int j = p & 7, lane = (p >> 3) & 63, kb = p >> 9;
        const int k  = kb * 32 + ((lane >> 4) << 3) + j;
        const int nn = t * 16 + (lane & 15);
        dst[p] = f2bf(src[(size_t)k * 128 + nn]);
    }
}

// ---------------------------------------------------------------------------
// Per-node stage-0 factorization:  Ur = h_node @ W0r + b0,  Uc = h_node @ W0c
// (bf16 out). Consumes kb 4..7 / 8..11 of the packed stage-0 slab.
// Runs immediately before each edge_mlp -> Ur/Uc are L3-hot (key: R6 showed
// producing them inside node_agg loses ~100MB/dispatch of L3 hits).
// ---------------------------------------------------------------------------
__global__ __launch_bounds__(256, 4) void u_gemm_kernel(
    const unsigned short* __restrict__ h_node_bf,
    const unsigned short* __restrict__ Wp0, const float* __restrict__ b0,
    unsigned short* __restrict__ Ur, unsigned short* __restrict__ Uc, int N)
{
    __shared__ __align__(16) unsigned short B[64][136];
    const int tid  = threadIdx.x;
    const int lane = tid & 63;
    const int wv   = tid >> 6;
    const int n0   = blockIdx.x * 64;

    {
        const int t = tid >> 2, q = tid & 3;
        const int node = n0 + t;
#pragma unroll
        for (int i = 0; i < 4; ++i) {
            const int k8 = (q + 4 * i) << 3;
            short8 v = (short8){0,0,0,0,0,0,0,0};
            if (node < N) v = *(const short8*)&h_node_bf[(size_t)node * 128 + k8];
            *(short8*)&B[t][k8] = v;
        }
    }
    wave_lds_fence();

    const int lr = lane & 15, lg = lane >> 4;
    floatx4 accr[8], accc[8];
#pragma unroll
    for (int nt = 0; nt < 8; ++nt) {
        const float4 bv = *(const float4*)&b0[nt * 16 + lg * 4];
        accr[nt] = (floatx4){bv.x, bv.y, bv.z, bv.w};
        accc[nt] = (floatx4){0.f, 0.f, 0.f, 0.f};
    }
    const unsigned short* brow = &B[wv * 16 + lr][0];
#pragma unroll 2
    for (int kb = 0; kb < 4; ++kb) {
        const short8 mf = *(const short8*)(brow + kb * 32 + lg * 8);
#pragma unroll
        for (int nt = 0; nt < 8; ++nt) {
            const short8 wr = *(const short8*)(Wp0 + ((size_t)(nt * 12 + 4 + kb) * 64 + lane) * 8);
            const short8 wc = *(const short8*)(Wp0 + ((size_t)(nt * 12 + 8 + kb) * 64 + lane) * 8);
            accr[nt] = __builtin_amdgcn_mfma_f32_16x16x32_bf16(wr, mf, accr[nt], 0, 0, 0);
            accc[nt] = __builtin_amdgcn_mfma_f32_16x16x32_bf16(wc, mf, accc[nt], 0, 0, 0);
        }
    }
    const int node = n0 + wv * 16 + lr;
    if (node < N) {
        unsigned short* rrow = Ur + (size_t)node * 128;
        unsigned short* crow = Uc + (size_t)node * 128;
#pragma unroll
        for (int nt = 0; nt < 8; ++nt) {
            uint2 o;
            o.x = f2bf_pk(accr[nt][0], accr[nt][1]);
            o.y = f2bf_pk(accr[nt][2], accr[nt][3]);
            *(uint2*)(rrow + nt * 16 + lg * 4) = o;
            o.x = f2bf_pk(accc[nt][0], accc[nt][1]);
            o.y = f2bf_pk(accc[nt][2], accc[nt][3]);
            *(uint2*)(crow + nt * 16 + lg * 4) = o;
        }
    }
}

// ---------------------------------------------------------------------------
// Sorted-edge MFMA edge MLP — round-18: R3 structure (best measured, 402us)
// with a 48-edge tile -> 24 KB LDS -> 6 blocks/CU (was 64-edge/32KB/4).
// One variable changed vs R3; everything else byte-identical.
// Tail block: index loads clamped; h_edge has a zeroed 16-row pad.
// ---------------------------------------------------------------------------
__global__ __launch_bounds__(256, 6) void edge_mlp_csr_kernel(
    const unsigned short* __restrict__ h_edge,
    const unsigned short* __restrict__ Ur, const unsigned short* __restrict__ Uc,
    const int* __restrict__ row_s, const int* __restrict__ col_s,
    const unsigned short* __restrict__ Wp, const float* __restrict__ bh)
{
    __shared__ __align__(16) unsigned short Xs[6144];   // 48 x 128, 12 KB
    __shared__ __align__(16) unsigned short Ys[6144];   // 12 KB

    const int tid  = threadIdx.x;
    const int e0   = blockIdx.x * ETILE_;
    const int lane = tid & 63;
    const int wv   = tid >> 6;
    const int lr   = lane & 15;
    const int lg   = lane >> 4;
    const int nt0  = 2 * wv, nt1 = nt0 + 1;

    // edge indices for this lane's 3 e-tiles (clamped for the tail block)
    int rid[3], cid[3];
#pragma unroll
    for (int et = 0; et < 3; ++et) {
        int e = e0 + et * 16 + lr;
        if (e >= N_EDGES_) e = N_EDGES_ - 1;
        rid[et] = row_s[e];
        cid[et] = col_s[e];
    }

    // async stage: Xs <- h_edge rows [0,48); wave wv stages rows [12wv,12wv+12)
    // chunk-swizzled source (slot c holds chunk c^(r&7)), linear LDS dest.
    // Pad rows (>= N_EDGES_) are zero-initialized in ws -> safe to stage.
    const int srow = 12 * wv + lg;
#pragma unroll
    for (int j = 0; j < 3; ++j) {
        const int r = srow + 4 * j;
        const int c = lr ^ (r & 7);
        gload_lds16(h_edge + (size_t)(e0 + r) * 128 + c * 8,
                    &Xs[(12 * wv + 4 * j) * 128]);
    }

    // per-lane U gathers in accumulator fragment layout (8B each)
    uint2 gr0[3], gr1[3], gc0[3], gc1[3];
#pragma unroll
    for (int et = 0; et < 3; ++et) {
        gr0[et] = *(const uint2*)(Ur + (size_t)rid[et] * 128 + nt0 * 16 + lg * 4);
        gr1[et] = *(const uint2*)(Ur + (size_t)rid[et] * 128 + nt1 * 16 + lg * 4);
        gc0[et] = *(const uint2*)(Uc + (size_t)cid[et] * 128 + nt0 * 16 + lg * 4);
        gc1[et] = *(const uint2*)(Uc + (size_t)cid[et] * 128 + nt1 * 16 + lg * 4);
    }

    asm volatile("s_waitcnt vmcnt(0)" ::: "memory");
    __syncthreads();

    // acc init = Ur[row] + Uc[col]   (b0 folded into Ur)
    floatx4 acc0[3], acc1[3];
#pragma unroll
    for (int et = 0; et < 3; ++et) {
#pragma unroll
        for (int j = 0; j < 2; ++j) {
            const unsigned ra = (j == 0) ? gr0[et].x : gr0[et].y;
            const unsigned ca = (j == 0) ? gc0[et].x : gc0[et].y;
            const unsigned rb = (j == 0) ? gr1[et].x : gr1[et].y;
            const unsigned cb = (j == 0) ? gc1[et].x : gc1[et].y;
            acc0[et][2 * j + 0] = bf2f((unsigned short)(ra & 0xFFFF)) + bf2f((unsigned short)(ca & 0xFFFF));
            acc0[et][2 * j + 1] = bf2f((unsigned short)(ra >> 16))    + bf2f((unsigned short)(ca >> 16));
            acc1[et][2 * j + 0] = bf2f((unsigned short)(rb & 0xFFFF)) + bf2f((unsigned short)(cb & 0xFFFF));
            acc1[et][2 * j + 1] = bf2f((unsigned short)(rb >> 16))    + bf2f((unsigned short)(cb >> 16));
        }
    }

    // ---- stage 0 : K = 128 over h_edge (kb 0..3 of the packed slab) -------
    const unsigned short* aptr0 = Wp + ((size_t)(nt0 * 12) * 64 + lane) * 8;
    const unsigned short* aptr1 = Wp + ((size_t)(nt1 * 12) * 64 + lane) * 8;
#pragma unroll 2
    for (int kk = 0; kk < 4; ++kk) {
        const short8 wf0 = *(const short8*)(aptr0 + (size_t)kk * 512);
        const short8 wf1 = *(const short8*)(aptr1 + (size_t)kk * 512);
#pragma unroll
        for (int et = 0; et < 3; ++et) {
            const int r = et * 16 + lr;
            const short8 mf = *(const short8*)&Xs[r * 128 + (((kk * 4 + lg) ^ (r & 7)) << 3)];
            acc0[et] = __builtin_amdgcn_mfma_f32_16x16x32_bf16(wf0, mf, acc0[et], 0, 0, 0);
            acc1[et] = __builtin_amdgcn_mfma_f32_16x16x32_bf16(wf1, mf, acc1[et], 0, 0, 0);
        }
    }

    // residual copy for epilogue, read from Xs while it is still intact
    // (Xs is next overwritten only after the barrier that follows stage 1)
    const int t_ = tid >> 2, q_ = tid & 3;
    short8 he_reg[4];
    if (t_ < ETILE_) {
#pragma unroll
        for (int i = 0; i < 4; ++i) {
            const int ch = q_ + 4 * i;
            he_reg[i] = *(const short8*)&Xs[t_ * 128 + ((ch ^ (t_ & 7)) << 3)];
        }
    }

    // stage-0 out -> Ys
#pragma unroll
    for (int et = 0; et < 3; ++et) {
        const int r = et * 16 + lr;
        uint2 p0, p1;
        p0.x = f2bf_pk(silu_f(acc0[et][0]), silu_f(acc0[et][1]));
        p0.y = f2bf_pk(silu_f(acc0[et][2]), silu_f(acc0[et][3]));
        p1.x = f2bf_pk(silu_f(acc1[et][0]), silu_f(acc1[et][1]));
        p1.y = f2bf_pk(silu_f(acc1[et][2]), silu_f(acc1[et][3]));
        const int c0 = (2 * nt0 + (lg >> 1)) ^ (r & 7);
        const int c1 = (2 * nt1 + (lg >> 1)) ^ (r & 7);
        *(uint2*)&Ys[r * 128 + c0 * 8 + (lg & 1) * 4] = p0;
        *(uint2*)&Ys[r * 128 + c1 * 8 + (lg & 1) * 4] = p1;
    }
    __syncthreads();

    // ---- stages 1..4 : K = 128, ping-pong Y->X->Y->X->Y -------------------
#pragma unroll 1
    for (int s = 1; s < 5; ++s) {
        const unsigned short* bin = (s & 1) ? Ys : Xs;
        unsigned short* bout      = (s & 1) ? Xs : Ys;
        const unsigned short* __restrict__ Ws = Wp + 49152 + (size_t)(s - 1) * 16384;
        const float* __restrict__ bias = bh + (size_t)(s - 1) * 128;

        const float4 bv0 = *(const float4*)&bias[nt0 * 16 + lg * 4];
        const float4 bv1 = *(const float4*)&bias[nt1 * 16 + lg * 4];
#pragma unroll
        for (int et = 0; et < 3; ++et) {
            acc0[et] = (floatx4){bv0.x, bv0.y, bv0.z, bv0.w};
            acc1[et] = (floatx4){bv1.x, bv1.y, bv1.z, bv1.w};
        }
        const unsigned short* ap0 = Ws + ((size_t)(nt0 * 4) * 64 + lane) * 8;
        const unsigned short* ap1 = Ws + ((size_t)(nt1 * 4) * 64 + lane) * 8;
#pragma unroll 2
        for (int kk = 0; kk < 4; ++kk) {
            const short8 wf0 = *(const short8*)(ap0 + (size_t)kk * 512);
            const short8 wf1 = *(const short8*)(ap1 + (size_t)kk * 512);
#pragma unroll
            for (int et = 0; et < 3; ++et) {
                const int r = et * 16 + lr;
                const short8 mf = *(const short8*)&bin[r * 128 + (((kk * 4 + lg) ^ (r & 7)) << 3)];
                acc0[et] = __builtin_amdgcn_mfma_f32_16x16x32_bf16(wf0, mf, acc0[et], 0, 0, 0);
                acc1[et] = __builtin_amdgcn_mfma_f32_16x16x32_bf16(wf1, mf, acc1[et], 0, 0, 0);
            }
        }
#pragma unroll
        for (int et = 0; et < 3; ++et) {
            const int r = et * 16 + lr;
            uint2 p0, p1;
            p0.x = f2bf_pk(silu_f(acc0[et][0]), silu_f(acc0[et][1]));
            p0.y = f2bf_pk(silu_f(acc0[et][2]), silu_f(acc0[et][3]));
            p1.x = f2bf_pk(silu_f(acc1[et][0]), silu_f(acc1[et][1]));
            p1.y = f2bf_pk(silu_f(acc1[et][2]), silu_f(acc1[et][3]));
            const int c0 = (2 * nt0 + (lg >> 1)) ^ (r & 7);
            const int c1 = (2 * nt1 + (lg >> 1)) ^ (r & 7);
            *(uint2*)&bout[r * 128 + c0 * 8 + (lg & 1) * 4] = p0;
            *(uint2*)&bout[r * 128 + c1 * 8 + (lg & 1) * 4] = p1;
        }
        __syncthreads();
    }

    // ---- epilogue: h_edge = he_reg + m (stage-4 out in Y); 16B stores -----
    if (t_ < ETILE_) {
#pragma unroll
        for (int i = 0; i < 4; ++i) {
            const int ch = q_ + 4 * i;
            const short8 mv = *(const short8*)&Ys[t_ * 128 + ((ch ^ (t_ & 7)) << 3)];
            const short8 ov = he_reg[i];
            float v[8];
#pragma unroll
            for (int j = 0; j < 8; ++j)
                v[j] = bf2f((unsigned short)ov[j]) + bf2f((unsigned short)mv[j]);
            uint4 sv;
            sv.x = f2bf_pk(v[0], v[1]);
            sv.y = f2bf_pk(v[2], v[3]);
            sv.z = f2bf_pk(v[4], v[5]);
            sv.w = f2bf_pk(v[6], v[7]);
            *(uint4*)(const_cast<unsigned short*>(h_edge) + (size_t)(e0 + t_) * 128 + ch * 8) = sv;
        }
    }
}

// ---------------------------------------------------------------------------
// Fused CSR segment-sum + MFMA node update:
//   agg[n] = sum of h_edge rows in [cursor[n]-hist[n], cursor[n])  (fp32)
//   h_node[n] += silu(agg @ node_w + node_b)
// ---------------------------------------------------------------------------
__global__ __launch_bounds__(256, 4) void node_agg_gemm_kernel(
    const unsigned short* __restrict__ h_edge,
    const int* __restrict__ hist, const int* __restrict__ cur_end,
    const unsigned short* __restrict__ Wpm, const float* __restrict__ bias,
    unsigned short* __restrict__ h_node_bf, int N)
{
    __shared__ __align__(16) unsigned short B[64][136];
    const int tid  = threadIdx.x;
    const int lane = tid & 63;
    const int wv   = tid >> 6;
    const int n0   = blockIdx.x * 64;

    {
        const int t = tid >> 2, q = tid & 3;
        const int n = n0 + t;
        float a[32];
#pragma unroll
        for (int j = 0; j < 32; ++j) a[j] = 0.f;
        if (n < N) {
            const int e_end = cur_end[n];
            const int e_beg = e_end - hist[n];
            for (int e = e_beg; e < e_end; ++e) {
                const unsigned short* p = &h_edge[(size_t)e * 128 + q * 32];
#pragma unroll
                for (int g = 0; g < 4; ++g) {
                    const short8 v = *(const short8*)(p + g * 8);
#pragma unroll
                    for (int j = 0; j < 8; ++j)
                        a[g * 8 + j] += bf2f((unsigned short)v[j]);
                }
            }
        }
#pragma unroll
        for (int g = 0; g < 4; ++g) {
            uint4 pk;
            pk.x = f2bf_pk(a[g * 8 + 0], a[g * 8 + 1]);
            pk.y = f2bf_pk(a[g * 8 + 2], a[g * 8 + 3]);
            pk.z = f2bf_pk(a[g * 8 + 4], a[g * 8 + 5]);
            pk.w = f2bf_pk(a[g * 8 + 6], a[g * 8 + 7]);
            *(uint4*)&B[t][q * 32 + g * 8] = pk;
        }
    }
    wave_lds_fence();

    const int lr = lane & 15, lg = lane >> 4;
    floatx4 acc[8];
#pragma unroll
    for (int nt = 0; nt < 8; ++nt) {
        const float4 bv = *(const float4*)&bias[nt * 16 + lg * 4];
        acc[nt] = (floatx4){bv.x, bv.y, bv.z, bv.w};
    }
    const unsigned short* brow = &B[wv * 16 + lr][0];
#pragma unroll 2
    for (int kb = 0; kb < 4; ++kb) {
        const short8 mf = *(const short8*)(brow + kb * 32 + lg * 8);
#pragma unroll
        for (int nt = 0; nt < 8; ++nt) {
            const short8 wf = *(const short8*)(Wpm + ((size_t)(nt * 4 + kb) * 64 + lane) * 8);
            acc[nt] = __builtin_amdgcn_mfma_f32_16x16x32_bf16(wf, mf, acc[nt], 0, 0, 0);
        }
    }
    const int node = n0 + wv * 16 + lr;
    if (node < N) {
        unsigned short* drow = &h_node_bf[(size_t)node * 128];
#pragma unroll
        for (int nt = 0; nt < 8; ++nt) {
            float x0 = silu_f(acc[nt][0]), x1 = silu_f(acc[nt][1]);
            float x2 = silu_f(acc[nt][2]), x3 = silu_f(acc[nt][3]);
            unsigned short* p = drow + nt * 16 + lg * 4;
            const uint2 d = *(const uint2*)p;
            x0 += bf2f((unsigned short)(d.x & 0xFFFF));
            x1 += bf2f((unsigned short)(d.x >> 16));
            x2 += bf2f((unsigned short)(d.y & 0xFFFF));
            x3 += bf2f((unsigned short)(d.y >> 16));
            uint2 o;
            o.x = f2bf_pk(x0, x1);
            o.y = f2bf_pk(x2, x3);
            *(uint2*)p = o;
        }
    }
}

// ---------------------------------------------------------------------------
// MFMA row GEMM (atom embedding): dst = gather(src)[z] @ W + b, bf16 out.
// ---------------------------------------------------------------------------
__global__ __launch_bounds__(256, 4) void atom_gemm_mfma_kernel(
    const float* __restrict__ src, const int* __restrict__ gidx,
    const unsigned short* __restrict__ Wpm, const float* __restrict__ bias,
    unsigned short* __restrict__ dst, int N)
{
    __shared__ __align__(16) unsigned short B[64][136];
    const int tid  = threadIdx.x;
    const int lane = tid & 63;
    const int wv   = tid >> 6;
    const int n0   = blockIdx.x * 64;

    {
        const int t = tid >> 2, q = tid & 3;
        const int node = n0 + t;
        const float* srow = src;
        if (node < N) srow = &src[(size_t)gidx[node] * 128];
#pragma unroll
        for (int i = 0; i < 4; ++i) {
            const int k8 = (q + 4 * i) << 3;
            uint4 pk = make_uint4(0, 0, 0, 0);
            if (node < N) {
                const float4 f0 = *(const float4*)(srow + k8);
                const float4 f1 = *(const float4*)(srow + k8 + 4);
                pk.x = f2bf_pk(f0.x, f0.y);
                pk.y = f2bf_pk(f0.z, f0.w);
                pk.z = f2bf_pk(f1.x, f1.y);
                pk.w = f2bf_pk(f1.z, f1.w);
            }
            *(uint4*)&B[t][k8] = pk;
        }
    }
    wave_lds_fence();

    const int lr = lane & 15, lg = lane >> 4;
    floatx4 acc[8];
#pragma unroll
    for (int nt = 0; nt < 8; ++nt) {
        const float4 bv = *(const float4*)&bias[nt * 16 + lg * 4];
        acc[nt] = (floatx4){bv.x, bv.y, bv.z, bv.w};
    }
    const unsigned short* brow = &B[wv * 16 + lr][0];
#pragma unroll 2
    for (int kb = 0; kb < 4; ++kb) {
        const short8 mf = *(const short8*)(brow + kb * 32 + lg * 8);
#pragma unroll
        for (int nt = 0; nt < 8; ++nt) {
            const short8 wf = *(const short8*)(Wpm + ((size_t)(nt * 4 + kb) * 64 + lane) * 8);
            acc[nt] = __builtin_amdgcn_mfma_f32_16x16x32_bf16(wf, mf, acc[nt], 0, 0, 0);
        }
    }
    const int node = n0 + wv * 16 + lr;
    if (node < N) {
        unsigned short* drow = &dst[(size_t)node * 128];
#pragma unroll
        for (int nt = 0; nt < 8; ++nt) {
            uint2 o;
            o.x = f2bf_pk(acc[nt][0], acc[nt][1]);
            o.y = f2bf_pk(acc[nt][2], acc[nt][3]);
            *(uint2*)(drow + nt * 16 + lg * 4) = o;
        }
    }
}

// ---------------------------------------------------------------------------
// MFMA edge embedding: basis [64,32] bf16 in LDS, one K=32 MFMA pass.
// ---------------------------------------------------------------------------
__global__ __launch_bounds__(256, 4) void edge_embed_mfma_kernel(
    const float* __restrict__ pos, const int* __restrict__ row, const int* __restrict__ col,
    const unsigned short* __restrict__ Wpe, const float* __restrict__ bemb,
    unsigned short* __restrict__ h_edge)
{
    __shared__ __align__(16) unsigned short Bas[64][40];
    const int tid  = threadIdx.x;
    const int lane = tid & 63;
    const int wv   = tid >> 6;
    const int e0   = blockIdx.x * 64;

    {
        const int t = tid >> 2, q = tid & 3;
        const int rr = row[e0 + t], cc = col[e0 + t];
        const float dx = pos[rr * 3 + 0] - pos[cc * 3 + 0];
        const float dy = pos[rr * 3 + 1] - pos[cc * 3 + 1];
        const float dz = pos[rr * 3 + 2] - pos[cc * 3 + 2];
        const float d = sqrtf(dx * dx + dy * dy + dz * dz);
        const float invs = 32.0f / 5.0f;
        float e[8];
#pragma unroll
        for (int j = 0; j < 8; ++j) {
            const float mu = (float)(q * 8 + j) * (5.0f / 31.0f);
            const float tt = (d - mu) * invs;
            e[j] = __expf(-0.5f * tt * tt);
        }
        uint4 pk;
        pk.x = f2bf_pk(e[0], e[1]);
        pk.y = f2bf_pk(e[2], e[3]);
        pk.z = f2bf_pk(e[4], e[5]);
        pk.w = f2bf_pk(e[6], e[7]);
        *(uint4*)&Bas[t][q * 8] = pk;
    }
    wave_lds_fence();

    const int lr = lane & 15, lg = lane >> 4;
    floatx4 acc[8];
#pragma unroll
    for (int nt = 0; nt < 8; ++nt) {
        const float4 bv = *(const float4*)&bemb[nt * 16 + lg * 4];
        acc[nt] = (floatx4){bv.x, bv.y, bv.z, bv.w};
    }
    const short8 mf = *(const short8*)&Bas[wv * 16 + lr][lg * 8];
#pragma unroll
    for (int nt = 0; nt < 8; ++nt) {
        const short8 wf = *(const short8*)(Wpe + ((size_t)nt * 64 + lane) * 8);
        acc[nt] = __builtin_amdgcn_mfma_f32_16x16x32_bf16(wf, mf, acc[nt], 0, 0, 0);
    }
    unsigned short* erow = &h_edge[(size_t)(e0 + wv * 16 + lr) * 128];
#pragma unroll
    for (int nt = 0; nt < 8; ++nt) {
        uint2 o;
        o.x = f2bf_pk(acc[nt][0], acc[nt][1]);
        o.y = f2bf_pk(acc[nt][2], acc[nt][3]);
        *(uint2*)(erow + nt * 16 + lg * 4) = o;
    }
}

// ---------------------------------------------------------------------------
// Graph pooling (bf16 node state) + output head.
// ---------------------------------------------------------------------------
__global__ __launch_bounds__(128) void pool_kernel(
    const unsigned short* __restrict__ h_node_bf, const int* __restrict__ batch,
    float* __restrict__ sums, float* __restrict__ cnt, int N)
{
    __shared__ int bb[256];
    const int tid = threadIdx.x;
    const int n0 = blockIdx.x * 256;
    for (int idx = tid; idx < 256; idx += 128) {
        int n = n0 + idx;
        bb[idx] = (n < N) ? batch[n] : -1;
    }
    __syncthreads();
    int cur = bb[0];
    float run = 0.f, runc = 0.f;
    for (int i = 0; i < 256; ++i) {
        const int b = bb[i];
        if (b < 0) break;
        if (b != cur) {
            atomicAdd(&sums[(size_t)cur * 128 + tid], run);
            if (tid == 0) atomicAdd(&cnt[cur], runc);
            run = 0.f; runc = 0.f; cur = b;
        }
        run += bf2f(h_node_bf[(size_t)(n0 + i) * 128 + tid]);
        runc += 1.f;
    }
    atomicAdd(&sums[(size_t)cur * 128 + tid], run);
    if (tid == 0) atomicAdd(&cnt[cur], runc);
}

__global__ __launch_bounds__(256) void final_kernel(
    const float* __restrict__ sums, const float* __restrict__ cnt,
    const float* __restrict__ out_w, const float* __restrict__ out_b,
    float* __restrict__ out)
{
    const int g = threadIdx.x;
    const float c = fmaxf(cnt[g], 1.0f);
    float acc = 0.f;
    for (int jj = 0; jj < 128; ++jj) acc = fmaf(sums[(size_t)g * 128 + jj], out_w[jj], acc);
    out[g] = acc / c + out_b[0];
}

__global__ void zero_out_kernel(float* out, int n) {
    int i = blockIdx.x * 256 + threadIdx.x;
    if (i < n) out[i] = 0.f;
}

// ---------------------------------------------------------------------------

extern "C" void kernel_launch(void* const* d_in, const int* in_sizes, int n_in,
                              void* d_out, int out_size, void* d_ws, size_t ws_size,
                              hipStream_t stream)
{
    const int*   z          = (const int*)  d_in[0];
    const float* pos        = (const float*)d_in[1];
    const int*   batch      = (const int*)  d_in[2];
    const int*   eidx       = (const int*)  d_in[3];
    const float* atom_table = (const float*)d_in[4];
    const float* atom_w     = (const float*)d_in[5];
    const float* atom_b     = (const float*)d_in[6];
    const float* edge_emb_w = (const float*)d_in[7];
    const float* edge_emb_b = (const float*)d_in[8];
    const float* edge_w0    = (const float*)d_in[9];
    const float* edge_b0    = (const float*)d_in[10];
    const float* edge_w     = (const float*)d_in[11];
    const float* edge_b     = (const float*)d_in[12];
    const float* node_w     = (const float*)d_in[13];
    const float* node_b     = (const float*)d_in[14];
    const float* out_w      = (const float*)d_in[15];
    const float* out_b      = (const float*)d_in[16];
    const int* row = eidx;
    const int* col = eidx + N_EDGES_;

    // ws layout (R3 footprint + 16 padded h_edge rows for the 48-edge tile).
    // Former fp32 agg buffer hosts Ur/Uc (bf16, 2x 12.8MB).
    float* aggb = (float*)d_ws;
    float* sums = aggb + (size_t)N_NODES_ * EMB;
    float* cnt  = sums + (size_t)N_GRAPH_ * EMB;
    unsigned short* h_node_bf = (unsigned short*)(cnt + N_GRAPH_);
    unsigned short* h_edge    = h_node_bf + (size_t)N_NODES_ * EMB;
    unsigned short* Wp        = h_edge + ((size_t)N_EDGES_ + EPAD_) * EMB;
    int* hist   = (int*)(Wp + WP_TOTAL);
    int* cursor = hist + N_NODES_;
    int* row_s  = cursor + N_NODES_;
    int* col_s  = row_s + N_EDGES_;

    unsigned short* Ur = (unsigned short*)aggb;
    unsigned short* Uc = Ur + (size_t)N_NODES_ * EMB;

    const size_t need = ((size_t)(N_NODES_ * EMB + N_GRAPH_ * EMB + N_GRAPH_)) * 4
                      + ((size_t)N_NODES_ * EMB + ((size_t)N_EDGES_ + EPAD_) * EMB + (size_t)WP_TOTAL) * 2
                      + ((size_t)N_NODES_ * 2 + (size_t)N_EDGES_ * 2) * 4;

    if (ws_size < need) {
        zero_out_kernel<<<1, 256, 0, stream>>>((float*)d_out, N_GRAPH_);
        return;
    }

    const int grid_rows64 = (N_NODES_ + 63) / 64;              // 782
    const int grid_edge   = (N_EDGES_ + ETILE_ - 1) / ETILE_;  // 16667

    (void)hipMemsetAsync(hist, 0, N_NODES_ * sizeof(int), stream);
    // zero the 16-row h_edge pad once (staged by tail blocks every layer)
    (void)hipMemsetAsync(h_edge + (size_t)N_EDGES_ * EMB, 0,
                         (size_t)EPAD_ * EMB * sizeof(unsigned short), stream);
    hist_kernel<<<(N_EDGES_ + 255) / 256, 256, 0, stream>>>(row, hist);
    scan_kernel<<<1, 256, 0, stream>>>(hist, cursor);
    scatter_kernel<<<(N_EDGES_ + 255) / 256, 256, 0, stream>>>(row, col, cursor, row_s, col_s);
    // post-scatter: cursor[n] = end offset, hist[n] = degree

    pack_w_kernel<<<256, 256, 0, stream>>>(edge_w0, edge_w, atom_w, node_w, edge_emb_w, Wp);

    atom_gemm_mfma_kernel<<<grid_rows64, 256, 0, stream>>>(
        atom_table, z, Wp + WP_ATOM, atom_b, h_node_bf, N_NODES_);
    edge_embed_mfma_kernel<<<N_EDGES_ / 64, 256, 0, stream>>>(
        pos, row_s, col_s, Wp + WP_EMB, edge_emb_b, h_edge);

    for (int l = 0; l < NLAYER_; ++l) {
        u_gemm_kernel<<<grid_rows64, 256, 0, stream>>>(
            h_node_bf, Wp + (size_t)l * 114688, edge_b0 + (size_t)l * 128,
            Ur, Uc, N_NODES_);
        edge_mlp_csr_kernel<<<grid_edge, 256, 0, stream>>>(
            h_edge, Ur, Uc, row_s, col_s,
            Wp + (size_t)l * 114688,
            edge_b + (size_t)l * 4 * 128);
        node_agg_gemm_kernel<<<grid_rows64, 256, 0, stream>>>(
            h_edge, hist, cursor,
            Wp + WP_NODE0 + (size_t)l * 16384, node_b + (size_t)l * 128,
            h_node_bf, N_NODES_);
    }

    (void)hipMemsetAsync(sums, 0, ((size_t)N_GRAPH_ * EMB + N_GRAPH_) * sizeof(float), stream);
    pool_kernel<<<(N_NODES_ + 255) / 256, 128, 0, stream>>>(h_node_bf, batch, sums, cnt, N_NODES_);
    final_kernel<<<1, 256, 0, stream>>>(sums, cnt, out_w, out_b, (float*)d_out);
}

// Round 8
// 2557.274 us; speedup vs baseline: 1.4259x; 1.0147x over previous
//
#include <hip/hip_runtime.h>

#define EMB      128
#define N_NODES_ 50000
#define N_EDGES_ 800000
#define N_GRAPH_ 256
#define NLAYER_  5

// packed-weight layout offsets (ushort elements)
#define WP_ATOM  573440
#define WP_NODE0 589824
#define WP_EMB   671744
#define WP_TOTAL 675840

typedef short short8 __attribute__((ext_vector_type(8)));
typedef float floatx4 __attribute__((ext_vector_type(4)));

__device__ __forceinline__ float silu_f(float x) {
    return __fdividef(x, 1.0f + __expf(-x));
}
__device__ __forceinline__ float bf2f(unsigned short h) {
    return __uint_as_float(((unsigned)h) << 16);
}
__device__ __forceinline__ unsigned short f2bf(float f) {
    unsigned u = __float_as_uint(f);
    unsigned r = 0x7FFFu + ((u >> 16) & 1u);
    return (unsigned short)((u + r) >> 16);
}

#if defined(__has_builtin)
#if __has_builtin(__builtin_amdgcn_cvt_pk_bf16_f32)
#define HAVE_PK_BF16 1
#endif
#endif
#ifdef HAVE_PK_BF16
typedef __bf16 bf16x2 __attribute__((ext_vector_type(2)));
__device__ __forceinline__ unsigned f2bf_pk(float a, float b) {
    bf16x2 v = __builtin_amdgcn_cvt_pk_bf16_f32(a, b);
    unsigned u;
    __builtin_memcpy(&u, &v, 4);
    return u;
}
#else
__device__ __forceinline__ unsigned f2bf_pk(float a, float b) {
    return (unsigned)f2bf(a) | ((unsigned)f2bf(b) << 16);
}
#endif

// wave-local LDS ordering (validated: correctness held)
__device__ __forceinline__ void wave_lds_fence() {
    __builtin_amdgcn_fence(__ATOMIC_ACQ_REL, "wavefront");
    __builtin_amdgcn_wave_barrier();
}

// async global -> LDS, 16B per lane. LDS dest = uniform base + lane*16.
__device__ __forceinline__ void gload_lds16(const unsigned short* g, unsigned short* l) {
    __builtin_amdgcn_global_load_lds(
        (const __attribute__((address_space(1))) void*)g,
        (__attribute__((address_space(3))) void*)l,
        16, 0, 0);
}

// ---------------------------------------------------------------------------
// Edge sort by destination row: histogram -> 1-block scan -> atomic scatter.
// ---------------------------------------------------------------------------
__global__ __launch_bounds__(256) void hist_kernel(
    const int* __restrict__ row, int* __restrict__ hist)
{
    const int e = blockIdx.x * 256 + threadIdx.x;
    if (e < N_EDGES_) atomicAdd(&hist[row[e]], 1);
}

__global__ __launch_bounds__(256) void scan_kernel(
    const int* __restrict__ hist, int* __restrict__ cursor)
{
    __shared__ int ssum[256];
    const int tid = threadIdx.x;
    const int chunk = (N_NODES_ + 255) / 256;
    const int base = tid * chunk;
    int s = 0;
    for (int i = 0; i < chunk; ++i) {
        const int idx = base + i;
        if (idx < N_NODES_) s += hist[idx];
    }
    ssum[tid] = s;
    __syncthreads();
    for (int off = 1; off < 256; off <<= 1) {
        const int t2 = (tid >= off) ? ssum[tid - off] : 0;
        __syncthreads();
        ssum[tid] += t2;
        __syncthreads();
    }
    int run = ssum[tid] - s;
    for (int i = 0; i < chunk; ++i) {
        const int idx = base + i;
        if (idx < N_NODES_) { cursor[idx] = run; run += hist[idx]; }
    }
}

__global__ __launch_bounds__(256) void scatter_kernel(
    const int* __restrict__ row, const int* __restrict__ col,
    int* __restrict__ cursor, int* __restrict__ row_s, int* __restrict__ col_s)
{
    const int e = blockIdx.x * 256 + threadIdx.x;
    if (e >= N_EDGES_) return;
    const int r = row[e];
    const int p = atomicAdd(&cursor[r], 1);
    row_s[p] = r;
    col_s[p] = col[e];
}

// ---------------------------------------------------------------------------
// Weight packing: fp32 [K][128] -> bf16 A-operand (W^T) fragment order.
// ---------------------------------------------------------------------------
__global__ __launch_bounds__(256) void pack_w_kernel(
    const float* __restrict__ edge_w0, const float* __restrict__ edge_w,
    const float* __restrict__ atom_w, const float* __restrict__ node_w,
    const float* __restrict__ edge_emb_w,
    unsigned short* __restrict__ Wp)
{
    const int bid = blockIdx.x;
    int Kb, t;
    const float* src;
    unsigned short* dst;
    if (bid < 200) {
        const int l = bid / 40, r = bid % 40, s = r / 8;
        t = r % 8;
        Kb = (s == 0) ? 12 : 4;
        src = (s == 0) ? edge_w0 + (size_t)l * 384 * 128
                       : edge_w + ((size_t)l * 4 + (s - 1)) * 128 * 128;
        dst = Wp + (size_t)l * 114688 + ((s == 0) ? 0 : (49152 + (s - 1) * 16384))
            + (size_t)t * Kb * 512;
    } else if (bid < 208) {
        t = bid - 200; Kb = 4; src = atom_w;
        dst = Wp + WP_ATOM + (size_t)t * Kb * 512;
    } else if (bid < 248) {
        const int l = (bid - 208) >> 3; t = (bid - 208) & 7; Kb = 4;
        src = node_w + (size_t)l * 128 * 128;
        dst = Wp + WP_NODE0 + (size_t)l * 16384 + (size_t)t * Kb * 512;
    } else {
        t = bid - 248; Kb = 1; src = edge_emb_w;
        dst = Wp + WP_EMB + (size_t)t * 512;
    }
    const int n = Kb * 512;
    for (int p = threadIdx.x; p < n; p += 256) {
        const int j = p & 7, lane = (p >> 3) & 63, kb = p >> 9;
        const int k  = kb * 32 + ((lane >> 4) << 3) + j;
        const int nn = t * 16 + (lane & 15);
        dst[p] = f2bf(src[(size_t)k * 128 + nn]);
    }
}

// ---------------------------------------------------------------------------
// Per-node stage-0 factorization:  Ur = h_node @ W0r + b0,  Uc = h_node @ W0c
// (bf16 out). Runs immediately before each edge_mlp -> Ur/Uc L3-hot.
// ---------------------------------------------------------------------------
__global__ __launch_bounds__(256, 4) void u_gemm_kernel(
    const unsigned short* __restrict__ h_node_bf,
    const unsigned short* __restrict__ Wp0, const float* __restrict__ b0,
    unsigned short* __restrict__ Ur, unsigned short* __restrict__ Uc, int N)
{
    __shared__ __align__(16) unsigned short B[64][136];
    const int tid  = threadIdx.x;
    const int lane = tid & 63;
    const int wv   = tid >> 6;
    const int n0   = blockIdx.x * 64;

    {
        const int t = tid >> 2, q = tid & 3;
        const int node = n0 + t;
#pragma unroll
        for (int i = 0; i < 4; ++i) {
            const int k8 = (q + 4 * i) << 3;
            short8 v = (short8){0,0,0,0,0,0,0,0};
            if (node < N) v = *(const short8*)&h_node_bf[(size_t)node * 128 + k8];
            *(short8*)&B[t][k8] = v;
        }
    }
    wave_lds_fence();

    const int lr = lane & 15, lg = lane >> 4;
    floatx4 accr[8], accc[8];
#pragma unroll
    for (int nt = 0; nt < 8; ++nt) {
        const float4 bv = *(const float4*)&b0[nt * 16 + lg * 4];
        accr[nt] = (floatx4){bv.x, bv.y, bv.z, bv.w};
        accc[nt] = (floatx4){0.f, 0.f, 0.f, 0.f};
    }
    const unsigned short* brow = &B[wv * 16 + lr][0];
#pragma unroll 2
    for (int kb = 0; kb < 4; ++kb) {
        const short8 mf = *(const short8*)(brow + kb * 32 + lg * 8);
#pragma unroll
        for (int nt = 0; nt < 8; ++nt) {
            const short8 wr = *(const short8*)(Wp0 + ((size_t)(nt * 12 + 4 + kb) * 64 + lane) * 8);
            const short8 wc = *(const short8*)(Wp0 + ((size_t)(nt * 12 + 8 + kb) * 64 + lane) * 8);
            accr[nt] = __builtin_amdgcn_mfma_f32_16x16x32_bf16(wr, mf, accr[nt], 0, 0, 0);
            accc[nt] = __builtin_amdgcn_mfma_f32_16x16x32_bf16(wc, mf, accc[nt], 0, 0, 0);
        }
    }
    const int node = n0 + wv * 16 + lr;
    if (node < N) {
        unsigned short* rrow = Ur + (size_t)node * 128;
        unsigned short* crow = Uc + (size_t)node * 128;
#pragma unroll
        for (int nt = 0; nt < 8; ++nt) {
            uint2 o;
            o.x = f2bf_pk(accr[nt][0], accr[nt][1]);
            o.y = f2bf_pk(accr[nt][2], accr[nt][3]);
            *(uint2*)(rrow + nt * 16 + lg * 4) = o;
            o.x = f2bf_pk(accc[nt][0], accc[nt][1]);
            o.y = f2bf_pk(accc[nt][2], accc[nt][3]);
            *(uint2*)(crow + nt * 16 + lg * 4) = o;
        }
    }
}

// ---------------------------------------------------------------------------
// helpers for the fully-unrolled edge MLP stages (compile-time LDS base)
// ---------------------------------------------------------------------------
__device__ __forceinline__ void bias_seed(const float* bias, int nt0, int nt1, int lg,
                                          floatx4 (&a0)[4], floatx4 (&a1)[4])
{
    const float4 bv0 = *(const float4*)&bias[nt0 * 16 + lg * 4];
    const float4 bv1 = *(const float4*)&bias[nt1 * 16 + lg * 4];
#pragma unroll
    for (int et = 0; et < 4; ++et) {
        a0[et] = (floatx4){bv0.x, bv0.y, bv0.z, bv0.w};
        a1[et] = (floatx4){bv1.x, bv1.y, bv1.z, bv1.w};
    }
}

template<int INB>
__device__ __forceinline__ void mlp_mfma(const char* lb, const int (&ro)[4][4],
    const unsigned short* ws0, const unsigned short* ws1,
    floatx4 (&a0)[4], floatx4 (&a1)[4])
{
#pragma unroll 2
    for (int kk = 0; kk < 4; ++kk) {
        const short8 wf0 = *(const short8*)(ws0 + (size_t)kk * 512);
        const short8 wf1 = *(const short8*)(ws1 + (size_t)kk * 512);
#pragma unroll
        for (int et = 0; et < 4; ++et) {
            const short8 mf = *(const short8*)(lb + INB + ro[et][kk]);
            a0[et] = __builtin_amdgcn_mfma_f32_16x16x32_bf16(wf0, mf, a0[et], 0, 0, 0);
            a1[et] = __builtin_amdgcn_mfma_f32_16x16x32_bf16(wf1, mf, a1[et], 0, 0, 0);
        }
    }
}

template<int OUTB>
__device__ __forceinline__ void mlp_store(char* lb, const int (&wo0)[4], const int (&wo1)[4],
    const floatx4 (&a0)[4], const floatx4 (&a1)[4])
{
#pragma unroll
    for (int et = 0; et < 4; ++et) {
        uint2 p0, p1;
        p0.x = f2bf_pk(silu_f(a0[et][0]), silu_f(a0[et][1]));
        p0.y = f2bf_pk(silu_f(a0[et][2]), silu_f(a0[et][3]));
        p1.x = f2bf_pk(silu_f(a1[et][0]), silu_f(a1[et][1]));
        p1.y = f2bf_pk(silu_f(a1[et][2]), silu_f(a1[et][3]));
        *(uint2*)(lb + OUTB + wo0[et]) = p0;
        *(uint2*)(lb + OUTB + wo1[et]) = p1;
    }
}

// ---------------------------------------------------------------------------
// Sorted-edge MFMA edge MLP — round-19: R3 structure (best measured, 402us)
// with the 5 stages FULLY UNROLLED and all LDS addressing hoisted:
//  - single 32KB LDS array; X = bytes [0,16384), Y = [16384,32768): the
//    ping-pong base is a compile-time template arg -> ds offset immediates.
//  - 16 read + 8 write swizzled byte offsets computed ONCE (stage-invariant).
//  - removes ~150 VALU insts/stage/wave of recomputed address arithmetic.
// ---------------------------------------------------------------------------
__global__ __launch_bounds__(256, 5) void edge_mlp_csr_kernel(
    unsigned short* __restrict__ h_edge,
    const unsigned short* __restrict__ Ur, const unsigned short* __restrict__ Uc,
    const int* __restrict__ row_s, const int* __restrict__ col_s,
    const unsigned short* __restrict__ Wp, const float* __restrict__ bh)
{
    __shared__ __align__(16) unsigned short Ls[16384];   // 32 KB: X | Y

    const int tid  = threadIdx.x;
    const int e0   = blockIdx.x * 64;
    const int lane = tid & 63;
    const int wv   = tid >> 6;
    const int lr   = lane & 15;
    const int lg   = lane >> 4;
    const int nt0  = 2 * wv, nt1 = nt0 + 1;

    // edge indices for this lane's 4 e-tiles
    int rid[4], cid[4];
#pragma unroll
    for (int et = 0; et < 4; ++et) {
        const int e = e0 + et * 16 + lr;
        rid[et] = row_s[e];
        cid[et] = col_s[e];
    }

    // async stage: X <- h_edge (chunk-swizzled source, linear LDS dest)
    const int srow = 16 * wv + lg;
#pragma unroll
    for (int j = 0; j < 4; ++j) {
        const int r = srow + 4 * j;
        const int c = lr ^ (r & 7);
        gload_lds16(h_edge + (size_t)(e0 + r) * 128 + c * 8,
                    &Ls[(16 * wv + 4 * j) * 128]);
    }

    // per-lane U gathers in accumulator fragment layout (8B each)
    uint2 gr0[4], gr1[4], gc0[4], gc1[4];
#pragma unroll
    for (int et = 0; et < 4; ++et) {
        gr0[et] = *(const uint2*)(Ur + (size_t)rid[et] * 128 + nt0 * 16 + lg * 4);
        gr1[et] = *(const uint2*)(Ur + (size_t)rid[et] * 128 + nt1 * 16 + lg * 4);
        gc0[et] = *(const uint2*)(Uc + (size_t)cid[et] * 128 + nt0 * 16 + lg * 4);
        gc1[et] = *(const uint2*)(Uc + (size_t)cid[et] * 128 + nt1 * 16 + lg * 4);
    }

    // stage-invariant swizzled LDS byte offsets
    char* const lb = (char*)Ls;
    int ro[4][4];                  // MFMA B-frag read offsets
    int wo0[4], wo1[4];            // C-frag write offsets
#pragma unroll
    for (int et = 0; et < 4; ++et) {
        const int r = et * 16 + lr;
#pragma unroll
        for (int kk = 0; kk < 4; ++kk)
            ro[et][kk] = r * 256 + (((kk * 4 + lg) ^ (r & 7)) << 4);
        const int c0 = (2 * nt0 + (lg >> 1)) ^ (r & 7);
        const int c1 = (2 * nt1 + (lg >> 1)) ^ (r & 7);
        wo0[et] = r * 256 + c0 * 16 + (lg & 1) * 8;
        wo1[et] = r * 256 + c1 * 16 + (lg & 1) * 8;
    }

    asm volatile("s_waitcnt vmcnt(0)" ::: "memory");
    __syncthreads();

    // acc seed = Ur[row] + Uc[col]   (b0 folded into Ur)
    floatx4 acc0[4], acc1[4];
#pragma unroll
    for (int et = 0; et < 4; ++et) {
        acc0[et][0] = bf2f((unsigned short)(gr0[et].x & 0xFFFF)) + bf2f((unsigned short)(gc0[et].x & 0xFFFF));
        acc0[et][1] = bf2f((unsigned short)(gr0[et].x >> 16))    + bf2f((unsigned short)(gc0[et].x >> 16));
        acc0[et][2] = bf2f((unsigned short)(gr0[et].y & 0xFFFF)) + bf2f((unsigned short)(gc0[et].y & 0xFFFF));
        acc0[et][3] = bf2f((unsigned short)(gr0[et].y >> 16))    + bf2f((unsigned short)(gc0[et].y >> 16));
        acc1[et][0] = bf2f((unsigned short)(gr1[et].x & 0xFFFF)) + bf2f((unsigned short)(gc1[et].x & 0xFFFF));
        acc1[et][1] = bf2f((unsigned short)(gr1[et].x >> 16))    + bf2f((unsigned short)(gc1[et].x >> 16));
        acc1[et][2] = bf2f((unsigned short)(gr1[et].y & 0xFFFF)) + bf2f((unsigned short)(gc1[et].y & 0xFFFF));
        acc1[et][3] = bf2f((unsigned short)(gr1[et].y >> 16))    + bf2f((unsigned short)(gc1[et].y >> 16));
    }

    // ---- stage 0 : in X(0) -> out Y(16384); h_edge kb 0..3 ----------------
    mlp_mfma<0>(lb, ro,
                Wp + ((size_t)(nt0 * 12) * 64 + lane) * 8,
                Wp + ((size_t)(nt1 * 12) * 64 + lane) * 8, acc0, acc1);

    // residual copy for epilogue, read from X while it is still intact
    // (X is next overwritten by stage 1, which is behind the next barrier)
    const int t_ = tid >> 2, q_ = tid & 3;
    short8 he_reg[4];
#pragma unroll
    for (int i = 0; i < 4; ++i) {
        const int ch = q_ + 4 * i;
        he_reg[i] = *(const short8*)(lb + t_ * 256 + ((ch ^ (t_ & 7)) << 4));
    }

    mlp_store<16384>(lb, wo0, wo1, acc0, acc1);
    __syncthreads();

    // hidden-stage weight bases (per-stage +16384 shorts folds at compile time)
    const unsigned short* wb0 = Wp + 49152 + ((size_t)(nt0 * 4) * 64 + lane) * 8;
    const unsigned short* wb1 = Wp + 49152 + ((size_t)(nt1 * 4) * 64 + lane) * 8;

    // ---- stage 1 : in Y -> out X ------------------------------------------
    bias_seed(bh + 0 * 128, nt0, nt1, lg, acc0, acc1);
    mlp_mfma<16384>(lb, ro, wb0 + 0 * 16384, wb1 + 0 * 16384, acc0, acc1);
    mlp_store<0>(lb, wo0, wo1, acc0, acc1);
    __syncthreads();

    // ---- stage 2 : in X -> out Y ------------------------------------------
    bias_seed(bh + 1 * 128, nt0, nt1, lg, acc0, acc1);
    mlp_mfma<0>(lb, ro, wb0 + 1 * 16384, wb1 + 1 * 16384, acc0, acc1);
    mlp_store<16384>(lb, wo0, wo1, acc0, acc1);
    __syncthreads();

    // ---- stage 3 : in Y -> out X ------------------------------------------
    bias_seed(bh + 2 * 128, nt0, nt1, lg, acc0, acc1);
    mlp_mfma<16384>(lb, ro, wb0 + 2 * 16384, wb1 + 2 * 16384, acc0, acc1);
    mlp_store<0>(lb, wo0, wo1, acc0, acc1);
    __syncthreads();

    // ---- stage 4 : in X -> out Y ------------------------------------------
    bias_seed(bh + 3 * 128, nt0, nt1, lg, acc0, acc1);
    mlp_mfma<0>(lb, ro, wb0 + 3 * 16384, wb1 + 3 * 16384, acc0, acc1);
    mlp_store<16384>(lb, wo0, wo1, acc0, acc1);
    __syncthreads();

    // ---- epilogue: h_edge = he_reg + m (stage-4 out in Y); 16B stores -----
#pragma unroll
    for (int i = 0; i < 4; ++i) {
        const int ch = q_ + 4 * i;
        const short8 mv = *(const short8*)(lb + 16384 + t_ * 256 + ((ch ^ (t_ & 7)) << 4));
        const short8 ov = he_reg[i];
        float v[8];
#pragma unroll
        for (int j = 0; j < 8; ++j)
            v[j] = bf2f((unsigned short)ov[j]) + bf2f((unsigned short)mv[j]);
        uint4 sv;
        sv.x = f2bf_pk(v[0], v[1]);
        sv.y = f2bf_pk(v[2], v[3]);
        sv.z = f2bf_pk(v[4], v[5]);
        sv.w = f2bf_pk(v[6], v[7]);
        *(uint4*)(h_edge + (size_t)(e0 + t_) * 128 + ch * 8) = sv;
    }
}

// ---------------------------------------------------------------------------
// Fused CSR segment-sum + MFMA node update:
//   agg[n] = sum of h_edge rows in [cursor[n]-hist[n], cursor[n])  (fp32)
//   h_node[n] += silu(agg @ node_w + node_b)
// ---------------------------------------------------------------------------
__global__ __launch_bounds__(256, 4) void node_agg_gemm_kernel(
    const unsigned short* __restrict__ h_edge,
    const int* __restrict__ hist, const int* __restrict__ cur_end,
    const unsigned short* __restrict__ Wpm, const float* __restrict__ bias,
    unsigned short* __restrict__ h_node_bf, int N)
{
    __shared__ __align__(16) unsigned short B[64][136];
    const int tid  = threadIdx.x;
    const int lane = tid & 63;
    const int wv   = tid >> 6;
    const int n0   = blockIdx.x * 64;

    {
        const int t = tid >> 2, q = tid & 3;
        const int n = n0 + t;
        float a[32];
#pragma unroll
        for (int j = 0; j < 32; ++j) a[j] = 0.f;
        if (n < N) {
            const int e_end = cur_end[n];
            const int e_beg = e_end - hist[n];
            for (int e = e_beg; e < e_end; ++e) {
                const unsigned short* p = &h_edge[(size_t)e * 128 + q * 32];
#pragma unroll
                for (int g = 0; g < 4; ++g) {
                    const short8 v = *(const short8*)(p + g * 8);
#pragma unroll
                    for (int j = 0; j < 8; ++j)
                        a[g * 8 + j] += bf2f((unsigned short)v[j]);
                }
            }
        }
#pragma unroll
        for (int g = 0; g < 4; ++g) {
            uint4 pk;
            pk.x = f2bf_pk(a[g * 8 + 0], a[g * 8 + 1]);
            pk.y = f2bf_pk(a[g * 8 + 2], a[g * 8 + 3]);
            pk.z = f2bf_pk(a[g * 8 + 4], a[g * 8 + 5]);
            pk.w = f2bf_pk(a[g * 8 + 6], a[g * 8 + 7]);
            *(uint4*)&B[t][q * 32 + g * 8] = pk;
        }
    }
    wave_lds_fence();

    const int lr = lane & 15, lg = lane >> 4;
    floatx4 acc[8];
#pragma unroll
    for (int nt = 0; nt < 8; ++nt) {
        const float4 bv = *(const float4*)&bias[nt * 16 + lg * 4];
        acc[nt] = (floatx4){bv.x, bv.y, bv.z, bv.w};
    }
    const unsigned short* brow = &B[wv * 16 + lr][0];
#pragma unroll 2
    for (int kb = 0; kb < 4; ++kb) {
        const short8 mf = *(const short8*)(brow + kb * 32 + lg * 8);
#pragma unroll
        for (int nt = 0; nt < 8; ++nt) {
            const short8 wf = *(const short8*)(Wpm + ((size_t)(nt * 4 + kb) * 64 + lane) * 8);
            acc[nt] = __builtin_amdgcn_mfma_f32_16x16x32_bf16(wf, mf, acc[nt], 0, 0, 0);
        }
    }
    const int node = n0 + wv * 16 + lr;
    if (node < N) {
        unsigned short* drow = &h_node_bf[(size_t)node * 128];
#pragma unroll
        for (int nt = 0; nt < 8; ++nt) {
            float x0 = silu_f(acc[nt][0]), x1 = silu_f(acc[nt][1]);
            float x2 = silu_f(acc[nt][2]), x3 = silu_f(acc[nt][3]);
            unsigned short* p = drow + nt * 16 + lg * 4;
            const uint2 d = *(const uint2*)p;
            x0 += bf2f((unsigned short)(d.x & 0xFFFF));
            x1 += bf2f((unsigned short)(d.x >> 16));
            x2 += bf2f((unsigned short)(d.y & 0xFFFF));
            x3 += bf2f((unsigned short)(d.y >> 16));
            uint2 o;
            o.x = f2bf_pk(x0, x1);
            o.y = f2bf_pk(x2, x3);
            *(uint2*)p = o;
        }
    }
}

// ---------------------------------------------------------------------------
// MFMA row GEMM (atom embedding): dst = gather(src)[z] @ W + b, bf16 out.
// ---------------------------------------------------------------------------
__global__ __launch_bounds__(256, 4) void atom_gemm_mfma_kernel(
    const float* __restrict__ src, const int* __restrict__ gidx,
    const unsigned short* __restrict__ Wpm, const float* __restrict__ bias,
    unsigned short* __restrict__ dst, int N)
{
    __shared__ __align__(16) unsigned short B[64][136];
    const int tid  = threadIdx.x;
    const int lane = tid & 63;
    const int wv   = tid >> 6;
    const int n0   = blockIdx.x * 64;

    {
        const int t = tid >> 2, q = tid & 3;
        const int node = n0 + t;
        const float* srow = src;
        if (node < N) srow = &src[(size_t)gidx[node] * 128];
#pragma unroll
        for (int i = 0; i < 4; ++i) {
            const int k8 = (q + 4 * i) << 3;
            uint4 pk = make_uint4(0, 0, 0, 0);
            if (node < N) {
                const float4 f0 = *(const float4*)(srow + k8);
                const float4 f1 = *(const float4*)(srow + k8 + 4);
                pk.x = f2bf_pk(f0.x, f0.y);
                pk.y = f2bf_pk(f0.z, f0.w);
                pk.z = f2bf_pk(f1.x, f1.y);
                pk.w = f2bf_pk(f1.z, f1.w);
            }
            *(uint4*)&B[t][k8] = pk;
        }
    }
    wave_lds_fence();

    const int lr = lane & 15, lg = lane >> 4;
    floatx4 acc[8];
#pragma unroll
    for (int nt = 0; nt < 8; ++nt) {
        const float4 bv = *(const float4*)&bias[nt * 16 + lg * 4];
        acc[nt] = (floatx4){bv.x, bv.y, bv.z, bv.w};
    }
    const unsigned short* brow = &B[wv * 16 + lr][0];
#pragma unroll 2
    for (int kb = 0; kb < 4; ++kb) {
        const short8 mf = *(const short8*)(brow + kb * 32 + lg * 8);
#pragma unroll
        for (int nt = 0; nt < 8; ++nt) {
            const short8 wf = *(const short8*)(Wpm + ((size_t)(nt * 4 + kb) * 64 + lane) * 8);
            acc[nt] = __builtin_amdgcn_mfma_f32_16x16x32_bf16(wf, mf, acc[nt], 0, 0, 0);
        }
    }
    const int node = n0 + wv * 16 + lr;
    if (node < N) {
        unsigned short* drow = &dst[(size_t)node * 128];
#pragma unroll
        for (int nt = 0; nt < 8; ++nt) {
            uint2 o;
            o.x = f2bf_pk(acc[nt][0], acc[nt][1]);
            o.y = f2bf_pk(acc[nt][2], acc[nt][3]);
            *(uint2*)(drow + nt * 16 + lg * 4) = o;
        }
    }
}

// ---------------------------------------------------------------------------
// MFMA edge embedding: basis [64,32] bf16 in LDS, one K=32 MFMA pass.
// ---------------------------------------------------------------------------
__global__ __launch_bounds__(256, 4) void edge_embed_mfma_kernel(
    const float* __restrict__ pos, const int* __restrict__ row, const int* __restrict__ col,
    const unsigned short* __restrict__ Wpe, const float* __restrict__ bemb,
    unsigned short* __restrict__ h_edge)
{
    __shared__ __align__(16) unsigned short Bas[64][40];
    const int tid  = threadIdx.x;
    const int lane = tid & 63;
    const int wv   = tid >> 6;
    const int e0   = blockIdx.x * 64;

    {
        const int t = tid >> 2, q = tid & 3;
        const int rr = row[e0 + t], cc = col[e0 + t];
        const float dx = pos[rr * 3 + 0] - pos[cc * 3 + 0];
        const float dy = pos[rr * 3 + 1] - pos[cc * 3 + 1];
        const float dz = pos[rr * 3 + 2] - pos[cc * 3 + 2];
        const float d = sqrtf(dx * dx + dy * dy + dz * dz);
        const float invs = 32.0f / 5.0f;
        float e[8];
#pragma unroll
        for (int j = 0; j < 8; ++j) {
            const float mu = (float)(q * 8 + j) * (5.0f / 31.0f);
            const float tt = (d - mu) * invs;
            e[j] = __expf(-0.5f * tt * tt);
        }
        uint4 pk;
        pk.x = f2bf_pk(e[0], e[1]);
        pk.y = f2bf_pk(e[2], e[3]);
        pk.z = f2bf_pk(e[4], e[5]);
        pk.w = f2bf_pk(e[6], e[7]);
        *(uint4*)&Bas[t][q * 8] = pk;
    }
    wave_lds_fence();

    const int lr = lane & 15, lg = lane >> 4;
    floatx4 acc[8];
#pragma unroll
    for (int nt = 0; nt < 8; ++nt) {
        const float4 bv = *(const float4*)&bemb[nt * 16 + lg * 4];
        acc[nt] = (floatx4){bv.x, bv.y, bv.z, bv.w};
    }
    const short8 mf = *(const short8*)&Bas[wv * 16 + lr][lg * 8];
#pragma unroll
    for (int nt = 0; nt < 8; ++nt) {
        const short8 wf = *(const short8*)(Wpe + ((size_t)nt * 64 + lane) * 8);
        acc[nt] = __builtin_amdgcn_mfma_f32_16x16x32_bf16(wf, mf, acc[nt], 0, 0, 0);
    }
    unsigned short* erow = &h_edge[(size_t)(e0 + wv * 16 + lr) * 128];
#pragma unroll
    for (int nt = 0; nt < 8; ++nt) {
        uint2 o;
        o.x = f2bf_pk(acc[nt][0], acc[nt][1]);
        o.y = f2bf_pk(acc[nt][2], acc[nt][3]);
        *(uint2*)(erow + nt * 16 + lg * 4) = o;
    }
}

// ---------------------------------------------------------------------------
// Graph pooling (bf16 node state) + output head.
// ---------------------------------------------------------------------------
__global__ __launch_bounds__(128) void pool_kernel(
    const unsigned short* __restrict__ h_node_bf, const int* __restrict__ batch,
    float* __restrict__ sums, float* __restrict__ cnt, int N)
{
    __shared__ int bb[256];
    const int tid = threadIdx.x;
    const int n0 = blockIdx.x * 256;
    for (int idx = tid; idx < 256; idx += 128) {
        int n = n0 + idx;
        bb[idx] = (n < N) ? batch[n] : -1;
    }
    __syncthreads();
    int cur = bb[0];
    float run = 0.f, runc = 0.f;
    for (int i = 0; i < 256; ++i) {
        const int b = bb[i];
        if (b < 0) break;
        if (b != cur) {
            atomicAdd(&sums[(size_t)cur * 128 + tid], run);
            if (tid == 0) atomicAdd(&cnt[cur], runc);
            run = 0.f; runc = 0.f; cur = b;
        }
        run += bf2f(h_node_bf[(size_t)(n0 + i) * 128 + tid]);
        runc += 1.f;
    }
    atomicAdd(&sums[(size_t)cur * 128 + tid], run);
    if (tid == 0) atomicAdd(&cnt[cur], runc);
}

__global__ __launch_bounds__(256) void final_kernel(
    const float* __restrict__ sums, const float* __restrict__ cnt,
    const float* __restrict__ out_w, const float* __restrict__ out_b,
    float* __restrict__ out)
{
    const int g = threadIdx.x;
    const float c = fmaxf(cnt[g], 1.0f);
    float acc = 0.f;
    for (int jj = 0; jj < 128; ++jj) acc = fmaf(sums[(size_t)g * 128 + jj], out_w[jj], acc);
    out[g] = acc / c + out_b[0];
}

__global__ void zero_out_kernel(float* out, int n) {
    int i = blockIdx.x * 256 + threadIdx.x;
    if (i < n) out[i] = 0.f;
}

// ---------------------------------------------------------------------------

extern "C" void kernel_launch(void* const* d_in, const int* in_sizes, int n_in,
                              void* d_out, int out_size, void* d_ws, size_t ws_size,
                              hipStream_t stream)
{
    const int*   z          = (const int*)  d_in[0];
    const float* pos        = (const float*)d_in[1];
    const int*   batch      = (const int*)  d_in[2];
    const int*   eidx       = (const int*)  d_in[3];
    const float* atom_table = (const float*)d_in[4];
    const float* atom_w     = (const float*)d_in[5];
    const float* atom_b     = (const float*)d_in[6];
    const float* edge_emb_w = (const float*)d_in[7];
    const float* edge_emb_b = (const float*)d_in[8];
    const float* edge_w0    = (const float*)d_in[9];
    const float* edge_b0    = (const float*)d_in[10];
    const float* edge_w     = (const float*)d_in[11];
    const float* edge_b     = (const float*)d_in[12];
    const float* node_w     = (const float*)d_in[13];
    const float* node_b     = (const float*)d_in[14];
    const float* out_w      = (const float*)d_in[15];
    const float* out_b      = (const float*)d_in[16];
    const int* row = eidx;
    const int* col = eidx + N_EDGES_;

    // ws layout (identical footprint to round 3 — known to fit).
    // The former fp32 agg buffer hosts Ur/Uc (bf16, 2x 12.8MB).
    float* aggb = (float*)d_ws;
    float* sums = aggb + (size_t)N_NODES_ * EMB;
    float* cnt  = sums + (size_t)N_GRAPH_ * EMB;
    unsigned short* h_node_bf = (unsigned short*)(cnt + N_GRAPH_);
    unsigned short* h_edge    = h_node_bf + (size_t)N_NODES_ * EMB;
    unsigned short* Wp        = h_edge + (size_t)N_EDGES_ * EMB;
    int* hist   = (int*)(Wp + WP_TOTAL);
    int* cursor = hist + N_NODES_;
    int* row_s  = cursor + N_NODES_;
    int* col_s  = row_s + N_EDGES_;

    unsigned short* Ur = (unsigned short*)aggb;
    unsigned short* Uc = Ur + (size_t)N_NODES_ * EMB;

    const size_t need = ((size_t)(N_NODES_ * EMB + N_GRAPH_ * EMB + N_GRAPH_)) * 4
                      + ((size_t)N_NODES_ * EMB + (size_t)N_EDGES_ * EMB + (size_t)WP_TOTAL) * 2
                      + ((size_t)N_NODES_ * 2 + (size_t)N_EDGES_ * 2) * 4;

    if (ws_size < need) {
        zero_out_kernel<<<1, 256, 0, stream>>>((float*)d_out, N_GRAPH_);
        return;
    }

    const int grid_rows64 = (N_NODES_ + 63) / 64;   // 782

    (void)hipMemsetAsync(hist, 0, N_NODES_ * sizeof(int), stream);
    hist_kernel<<<(N_EDGES_ + 255) / 256, 256, 0, stream>>>(row, hist);
    scan_kernel<<<1, 256, 0, stream>>>(hist, cursor);
    scatter_kernel<<<(N_EDGES_ + 255) / 256, 256, 0, stream>>>(row, col, cursor, row_s, col_s);
    // post-scatter: cursor[n] = end offset, hist[n] = degree

    pack_w_kernel<<<256, 256, 0, stream>>>(edge_w0, edge_w, atom_w, node_w, edge_emb_w, Wp);

    atom_gemm_mfma_kernel<<<grid_rows64, 256, 0, stream>>>(
        atom_table, z, Wp + WP_ATOM, atom_b, h_node_bf, N_NODES_);
    edge_embed_mfma_kernel<<<N_EDGES_ / 64, 256, 0, stream>>>(
        pos, row_s, col_s, Wp + WP_EMB, edge_emb_b, h_edge);

    for (int l = 0; l < NLAYER_; ++l) {
        u_gemm_kernel<<<grid_rows64, 256, 0, stream>>>(
            h_node_bf, Wp + (size_t)l * 114688, edge_b0 + (size_t)l * 128,
            Ur, Uc, N_NODES_);
        edge_mlp_csr_kernel<<<N_EDGES_ / 64, 256, 0, stream>>>(
            h_edge, Ur, Uc, row_s, col_s,
            Wp + (size_t)l * 114688,
            edge_b + (size_t)l * 4 * 128);
        node_agg_gemm_kernel<<<grid_rows64, 256, 0, stream>>>(
            h_edge, hist, cursor,
            Wp + WP_NODE0 + (size_t)l * 16384, node_b + (size_t)l * 128,
            h_node_bf, N_NODES_);
    }

    (void)hipMemsetAsync(sums, 0, ((size_t)N_GRAPH_ * EMB + N_GRAPH_) * sizeof(float), stream);
    pool_kernel<<<(N_NODES_ + 255) / 256, 128, 0, stream>>>(h_node_bf, batch, sums, cnt, N_NODES_);
    final_kernel<<<1, 256, 0, stream>>>(sums, cnt, out_w, out_b, (float*)d_out);
}